// Round 10
// baseline (1078.326 us; speedup 1.0000x reference)
//
#include <hip/hip_runtime.h>

#define D 64
#define BCH 4096
#define NS 16
#define SSH 13  // slice = src >> SSH (valid for N <= 131072)

typedef __attribute__((ext_vector_type(8))) _Float16 f16x8;
typedef __attribute__((ext_vector_type(4))) float f32x4;

__device__ __forceinline__ float sigmoidf_(float x) {
    return 1.0f / (1.0f + __expf(-x));
}
__device__ __forceinline__ float h2f(ushort u) {
    _Float16 h;
    __builtin_memcpy(&h, &u, 2);
    return (float)h;
}
__device__ __forceinline__ ushort f2h(float f) {
    _Float16 h = (_Float16)f;
    ushort u;
    __builtin_memcpy(&u, &h, 2);
    return u;
}
__device__ __forceinline__ float2 up2(uint v) {
    float2 r;
    r.x = h2f((ushort)(v & 0xffffu));
    r.y = h2f((ushort)(v >> 16));
    return r;
}

// ---------------- CSR build: bucket sort by (slice(src), dst) ----------------
// bucket = slice*NBd + (dst>>10); packed entry = (src<<10)|(dst&1023)

__global__ __launch_bounds__(256) void bin_edges(const int* __restrict__ src,
                                                 const int* __restrict__ dst,
                                                 int* __restrict__ bcur,
                                                 uint* __restrict__ bins,
                                                 int CAP, int NBd, int NB2, int E) {
    __shared__ uint lp[BCH];
    __shared__ ushort lb[BCH];
    __shared__ int hist[1600], base[1600];
    int t = threadIdx.x;
    int e0 = blockIdx.x * BCH;
    for (int k = t; k < NB2; k += 256) hist[k] = 0;
    __syncthreads();
    for (int k = t; k < BCH; k += 256) {
        int e = e0 + k;
        uint p = 0xFFFFFFFFu;
        int b = 0;
        if (e < E) {
            int s_ = src[e];
            int d_ = dst[e];
            b = (s_ >> SSH) * NBd + (d_ >> 10);
            atomicAdd(&hist[b], 1);
            p = ((uint)s_ << 10) | (uint)(d_ & 1023);
        }
        lp[k] = p;
        lb[k] = (ushort)b;
    }
    __syncthreads();
    for (int k = t; k < NB2; k += 256) {
        int c = hist[k];
        base[k] = (c > 0) ? atomicAdd(&bcur[k], c) : 0;
        hist[k] = 0;
    }
    __syncthreads();
    for (int k = t; k < BCH; k += 256) {
        uint p = lp[k];
        if (p != 0xFFFFFFFFu) {
            int b = lb[k];
            int pos = base[b] + atomicAdd(&hist[b], 1);
            bins[(size_t)b * CAP + pos] = p;
        }
    }
}

// exclusive scan over NB2 buckets (<=2048), 256 threads x 8 each;
// also writes csr4[s][N] slice-end sentinels.
__global__ __launch_bounds__(256) void scan2(const int* __restrict__ bcur,
                                             int* __restrict__ boff,
                                             int* __restrict__ csr4,
                                             int NBd, int NB2, int N, int E) {
    __shared__ int part[256];
    int t = threadIdx.x;
    int sum8 = 0;
#pragma unroll
    for (int i = 0; i < 8; i++) {
        int idx = t * 8 + i;
        if (idx < NB2) sum8 += bcur[idx];
    }
    part[t] = sum8;
    __syncthreads();
    for (int o = 1; o < 256; o <<= 1) {
        int x = (t >= o) ? part[t - o] : 0;
        __syncthreads();
        part[t] += x;
        __syncthreads();
    }
    int run = part[t] - sum8;
#pragma unroll
    for (int i = 0; i < 8; i++) {
        int idx = t * 8 + i;
        if (idx < NB2) {
            boff[idx] = run;
            run += bcur[idx];
        }
    }
    __syncthreads();
    if (t < NS) {
        size_t NP1 = (size_t)N + 1;
        int endv = (t + 1 < NS) ? boff[(t + 1) * NBd] : E;
        csr4[t * NP1 + N] = endv;
    }
}

// one block per bucket: per-node hist -> scan -> csr4 starts -> localized scatter
__global__ __launch_bounds__(256) void build_csr(const uint* __restrict__ bins,
                                                 const int* __restrict__ bcur,
                                                 const int* __restrict__ boff,
                                                 int* __restrict__ csr4,
                                                 int* __restrict__ sorted,
                                                 int CAP, int NBd, int N) {
    __shared__ int hist[1024];
    __shared__ int part[256];
    int t = threadIdx.x;
    int b = blockIdx.x;
    int s = b / NBd;
    int dloc0 = (b % NBd) << 10;
    size_t NP1 = (size_t)N + 1;
    int cnt = bcur[b];
    int e0 = boff[b];
    const uint* bp = bins + (size_t)b * CAP;
    for (int k = t; k < 1024; k += 256) hist[k] = 0;
    __syncthreads();
    for (int k = t; k < cnt; k += 256) atomicAdd(&hist[bp[k] & 1023u], 1);
    __syncthreads();
    int v0 = hist[4 * t], v1 = hist[4 * t + 1], v2 = hist[4 * t + 2], v3 = hist[4 * t + 3];
    part[t] = v0 + v1 + v2 + v3;
    __syncthreads();
    for (int o = 1; o < 256; o <<= 1) {
        int x = (t >= o) ? part[t - o] : 0;
        __syncthreads();
        part[t] += x;
        __syncthreads();
    }
    int run = (t > 0) ? part[t - 1] : 0;
    int pre[4];
    pre[0] = run;
    pre[1] = run + v0;
    pre[2] = run + v0 + v1;
    pre[3] = run + v0 + v1 + v2;
    __syncthreads();
    hist[4 * t + 0] = e0 + pre[0];
    hist[4 * t + 1] = e0 + pre[1];
    hist[4 * t + 2] = e0 + pre[2];
    hist[4 * t + 3] = e0 + pre[3];
#pragma unroll
    for (int j = 0; j < 4; j++) {
        int node = dloc0 + 4 * t + j;
        if (node < N) csr4[s * NP1 + node] = e0 + pre[j];
    }
    __syncthreads();
    for (int k = t; k < cnt; k += 256) {
        uint p = bp[k];
        int pos = atomicAdd(&hist[p & 1023u], 1);
        sorted[pos] = (int)(p >> 10);
    }
}

// deg(n) = sum_s subdeg; dinv/rdinv
__global__ __launch_bounds__(256) void deg_dinv(const int* __restrict__ csr4,
                                                float* __restrict__ dinv,
                                                float* __restrict__ rdinv, int N) {
    int n = blockIdx.x * 256 + threadIdx.x;
    if (n >= N) return;
    size_t NP1 = (size_t)N + 1;
    int deg = 0;
    for (int s = 0; s < NS; s++)
        deg += csr4[s * NP1 + n + 1] - csr4[s * NP1 + n];
    float c = (float)deg + 1.0f;
    dinv[n] = rsqrtf(c);
    rdinv[n] = sqrtf(c);
}

// ---------------- prep ----------------

__global__ __launch_bounds__(256) void prep_xd(const float* __restrict__ x,
                                               const float* __restrict__ dinv,
                                               ushort* __restrict__ actd, int N16) {
    int p = blockIdx.x * 256 + threadIdx.x;
    if (p >= N16) return;
    int n = p >> 4;
    float d = dinv[n];
    float4 v = reinterpret_cast<const float4*>(x)[p];
    ushort4 o;
    o.x = f2h(v.x * d);
    o.y = f2h(v.y * d);
    o.z = f2h(v.z * d);
    o.w = f2h(v.w * d);
    reinterpret_cast<ushort4*>(actd)[p] = o;
}

__global__ __launch_bounds__(256) void wprep(const float* __restrict__ W,
                                             ushort* __restrict__ wfrag) {
    int idx = blockIdx.x * 256 + threadIdx.x;
    if (idx >= 4096) return;
    int i = idx & 7;
    int lane = (idx >> 3) & 63;
    int hc = idx >> 9;
    int h = hc >> 2, c = hc & 3;
    int k = h * 32 + (lane >> 4) * 8 + i;
    int j = c * 16 + (lane & 15);
    wfrag[idx] = f2h(W[k * 64 + j]);
}

__global__ __launch_bounds__(256) void layer_prep(const float* __restrict__ ssum,
                                                  const float* __restrict__ sssq,
                                                  const float* __restrict__ gamma,
                                                  const float* __restrict__ beta,
                                                  const float* __restrict__ W,
                                                  float* __restrict__ A,
                                                  float* __restrict__ C,
                                                  float* __restrict__ u,
                                                  ushort* __restrict__ wfrag,
                                                  float invN) {
    __shared__ float As[64], Cs[64];
    int t = threadIdx.x;
    if (t < 64) {
        float m = ssum[t] * invN;
        float var = sssq[t] * invN - m * m;
        float rs = rsqrtf(var + 1e-4f);
        float a = rs * gamma[t];
        As[t] = a;
        A[t] = a;
        float c = fmaf(-m, a, beta[t]);
        Cs[t] = c;
        C[t] = c;
    }
    __syncthreads();
    if (t < 64) {
        float s = 0.f;
        for (int k = 0; k < 64; k++) s = fmaf(Cs[k], W[k * 64 + t], s);
        u[t] = s;
    }
    for (int idx = t; idx < 4096; idx += 256) {
        int i = idx & 7;
        int lane = (idx >> 3) & 63;
        int hc = idx >> 9;
        int h = hc >> 2, c = hc & 3;
        int k = h * 32 + (lane >> 4) * 8 + i;
        int j = c * 16 + (lane & 15);
        wfrag[idx] = f2h(W[k * 64 + j] * As[k]);
    }
}

__global__ __launch_bounds__(64) void finalize_aff(const float* __restrict__ ssum,
                                                   const float* __restrict__ sssq,
                                                   const float* __restrict__ gamma,
                                                   const float* __restrict__ beta,
                                                   float* __restrict__ A,
                                                   float* __restrict__ C, float invN) {
    int c = threadIdx.x;
    float m = ssum[c] * invN;
    float var = sssq[c] * invN - m * m;
    float rs = rsqrtf(var + 1e-4f);
    float a = rs * gamma[c];
    A[c] = a;
    C[c] = fmaf(-m, a, beta[c]);
}

// ---------------- aggregation: slice-ordered (L2-resident window) ----------------

// 128B rows, feature = lane.
__global__ __launch_bounds__(256) void agg_g(const ushort* __restrict__ actd,
                                             const int* __restrict__ csr4,
                                             const int* __restrict__ srcs,
                                             const float* __restrict__ dinv,
                                             const float* __restrict__ rdinv,
                                             ushort* __restrict__ zh,
                                             float* __restrict__ ssum,
                                             float* __restrict__ sssq,
                                             float* __restrict__ qout, int N, int E) {
    __shared__ float red[2][4][64];
    int lane = threadIdx.x & 63;
    int wv = threadIdx.x >> 6;
    int l7 = lane & 7;
    int Em1 = E - 1;
    const bool do_stats = (ssum != nullptr);
    const bool do_q = (qout != nullptr);
    size_t NP1 = (size_t)N + 1;
    float ps = 0.f, pq = 0.f;
    for (int n = blockIdx.x * 4 + wv; n < N; n += gridDim.x * 4) {
        float self = h2f(actd[((size_t)n << 6) + lane]);
        float acc = self;
        float dn = dinv[n];
        if (do_stats) {
            float a = self * rdinv[n];
            ps += a;
            pq += a * a;
        }
        float qa = 0.f;
        for (int s = 0; s < NS; s++) {
            int sb = csr4[s * NP1 + n];
            int d = csr4[s * NP1 + n + 1] - sb;
            while (d > 0) {
                int take = (d > 8) ? 8 : d;
                int idx8 = srcs[min(sb + l7, Em1)];
                if (take == 8) {
                    float t0, t1, t2, t3, t4, t5, t6, t7;
                    int u0 = __builtin_amdgcn_readlane(idx8, 0);
                    int u1 = __builtin_amdgcn_readlane(idx8, 1);
                    int u2 = __builtin_amdgcn_readlane(idx8, 2);
                    int u3 = __builtin_amdgcn_readlane(idx8, 3);
                    int u4 = __builtin_amdgcn_readlane(idx8, 4);
                    int u5 = __builtin_amdgcn_readlane(idx8, 5);
                    int u6 = __builtin_amdgcn_readlane(idx8, 6);
                    int u7 = __builtin_amdgcn_readlane(idx8, 7);
                    t0 = h2f(actd[((size_t)u0 << 6) + lane]);
                    t1 = h2f(actd[((size_t)u1 << 6) + lane]);
                    t2 = h2f(actd[((size_t)u2 << 6) + lane]);
                    t3 = h2f(actd[((size_t)u3 << 6) + lane]);
                    t4 = h2f(actd[((size_t)u4 << 6) + lane]);
                    t5 = h2f(actd[((size_t)u5 << 6) + lane]);
                    t6 = h2f(actd[((size_t)u6 << 6) + lane]);
                    t7 = h2f(actd[((size_t)u7 << 6) + lane]);
                    if (do_q) qa += ((dinv[u0] + dinv[u1]) + (dinv[u2] + dinv[u3])) +
                                    ((dinv[u4] + dinv[u5]) + (dinv[u6] + dinv[u7]));
                    acc += ((t0 + t1) + (t2 + t3)) + ((t4 + t5) + (t6 + t7));
                } else {
                    for (int j = 0; j < take; j++) {
                        int u = __builtin_amdgcn_readlane(idx8, j);
                        acc += h2f(actd[((size_t)u << 6) + lane]);
                        if (do_q) qa += dinv[u];
                    }
                }
                sb += take;
                d -= take;
            }
        }
        if (do_q && lane == 0) qout[n] = dn * (dn + qa);
        zh[((size_t)n << 6) + lane] = f2h(acc * dn);
    }
    if (do_stats) {
        red[0][wv][lane] = ps;
        red[1][wv][lane] = pq;
        __syncthreads();
        if (wv == 0) {
            float t0 = red[0][0][lane] + red[0][1][lane] + red[0][2][lane] + red[0][3][lane];
            float t1 = red[1][0][lane] + red[1][1][lane] + red[1][2][lane] + red[1][3][lane];
            atomicAdd(&ssum[lane], t0);
            atomicAdd(&sssq[lane], t1);
        }
    }
}

// 256B rows (att|str interleaved), features 2*lane, 2*lane+1.
__global__ __launch_bounds__(256) void agg_dual(const ushort* __restrict__ ab,
                                                const int* __restrict__ csr4,
                                                const int* __restrict__ srcs,
                                                const float* __restrict__ dinv,
                                                const float* __restrict__ rdinv,
                                                ushort* __restrict__ zab,
                                                float* __restrict__ ssA,
                                                float* __restrict__ sqA,
                                                float* __restrict__ ssS,
                                                float* __restrict__ sqS,
                                                int N, int E) {
    __shared__ float red[2][4][128];
    int lane = threadIdx.x & 63;
    int wv = threadIdx.x >> 6;
    int l7 = lane & 7;
    int Em1 = E - 1;
    size_t NP1 = (size_t)N + 1;
    float2 ps = make_float2(0.f, 0.f), pq = make_float2(0.f, 0.f);
    for (int n = blockIdx.x * 4 + wv; n < N; n += gridDim.x * 4) {
        uint su = *reinterpret_cast<const uint*>(ab + ((size_t)n << 7) + (lane << 1));
        float2 acc = up2(su);
        float dn = dinv[n];
        {
            float r = rdinv[n];
            float ax = acc.x * r, ay = acc.y * r;
            ps.x += ax; ps.y += ay;
            pq.x += ax * ax; pq.y += ay * ay;
        }
        for (int s = 0; s < NS; s++) {
            int sb = csr4[s * NP1 + n];
            int d = csr4[s * NP1 + n + 1] - sb;
            while (d > 0) {
                int take = (d > 8) ? 8 : d;
                int idx8 = srcs[min(sb + l7, Em1)];
                if (take == 8) {
                    uint v0, v1, v2, v3, v4, v5, v6, v7;
                    int u0 = __builtin_amdgcn_readlane(idx8, 0);
                    int u1 = __builtin_amdgcn_readlane(idx8, 1);
                    int u2 = __builtin_amdgcn_readlane(idx8, 2);
                    int u3 = __builtin_amdgcn_readlane(idx8, 3);
                    int u4 = __builtin_amdgcn_readlane(idx8, 4);
                    int u5 = __builtin_amdgcn_readlane(idx8, 5);
                    int u6 = __builtin_amdgcn_readlane(idx8, 6);
                    int u7 = __builtin_amdgcn_readlane(idx8, 7);
                    v0 = *reinterpret_cast<const uint*>(ab + ((size_t)u0 << 7) + (lane << 1));
                    v1 = *reinterpret_cast<const uint*>(ab + ((size_t)u1 << 7) + (lane << 1));
                    v2 = *reinterpret_cast<const uint*>(ab + ((size_t)u2 << 7) + (lane << 1));
                    v3 = *reinterpret_cast<const uint*>(ab + ((size_t)u3 << 7) + (lane << 1));
                    v4 = *reinterpret_cast<const uint*>(ab + ((size_t)u4 << 7) + (lane << 1));
                    v5 = *reinterpret_cast<const uint*>(ab + ((size_t)u5 << 7) + (lane << 1));
                    v6 = *reinterpret_cast<const uint*>(ab + ((size_t)u6 << 7) + (lane << 1));
                    v7 = *reinterpret_cast<const uint*>(ab + ((size_t)u7 << 7) + (lane << 1));
                    float2 f0 = up2(v0), f1 = up2(v1), f2 = up2(v2), f3 = up2(v3);
                    float2 f4 = up2(v4), f5 = up2(v5), f6 = up2(v6), f7 = up2(v7);
                    acc.x += ((f0.x + f1.x) + (f2.x + f3.x)) + ((f4.x + f5.x) + (f6.x + f7.x));
                    acc.y += ((f0.y + f1.y) + (f2.y + f3.y)) + ((f4.y + f5.y) + (f6.y + f7.y));
                } else {
                    for (int j = 0; j < take; j++) {
                        int u = __builtin_amdgcn_readlane(idx8, j);
                        uint v = *reinterpret_cast<const uint*>(ab + ((size_t)u << 7) + (lane << 1));
                        float2 f = up2(v);
                        acc.x += f.x;
                        acc.y += f.y;
                    }
                }
                sb += take;
                d -= take;
            }
        }
        uint pk = (uint)f2h(acc.x * dn) | ((uint)f2h(acc.y * dn) << 16);
        *reinterpret_cast<uint*>(zab + ((size_t)n << 7) + (lane << 1)) = pk;
    }
    red[0][wv][2 * lane + 0] = ps.x;
    red[0][wv][2 * lane + 1] = ps.y;
    red[1][wv][2 * lane + 0] = pq.x;
    red[1][wv][2 * lane + 1] = pq.y;
    __syncthreads();
    if (wv == 0) {
#pragma unroll
        for (int m0 = 0; m0 < 2; m0++) {
            int m = lane + m0 * 64;
            float t0 = red[0][0][m] + red[0][1][m] + red[0][2][m] + red[0][3][m];
            float t1 = red[1][0][m] + red[1][1][m] + red[1][2][m] + red[1][3][m];
            if (m < 64) {
                atomicAdd(&ssA[m], t0);
                atomicAdd(&sqA[m], t1);
            } else {
                atomicAdd(&ssS[m - 64], t0);
                atomicAdd(&sqS[m - 64], t1);
            }
        }
    }
}

// ---------------- MFMA GEMM ----------------
// OM: 0 = write fp16(act*dinv); 1 = stats only; 2 = apply affine, write f32.
template <int MODE, bool HAS_AFF, int OM>
__global__ __launch_bounds__(256) void gemm_mfma(const ushort* __restrict__ zh, int is,
                                                 const ushort* __restrict__ wfrag,
                                                 const float* __restrict__ bias,
                                                 const float* __restrict__ u,
                                                 const float* __restrict__ q,
                                                 const float* __restrict__ dinv,
                                                 ushort* __restrict__ outh, int os,
                                                 float* __restrict__ outf,
                                                 float* __restrict__ s0,
                                                 float* __restrict__ s1, int N) {
    int tid = threadIdx.x;
    int lane = tid & 63;
    int wv = tid >> 6;
    int l15 = lane & 15;
    int lg = lane >> 4;
    int tb = blockIdx.x * 64;

    const ushort* zrow = zh + (size_t)(tb + wv * 16 + l15) * is + (lg << 3);
    f16x8 a0 = *reinterpret_cast<const f16x8*>(zrow);
    f16x8 a1 = *reinterpret_cast<const f16x8*>(zrow + 32);

    const f16x8* wf = reinterpret_cast<const f16x8*>(wfrag) + lane;

    f32x4 acc[4];
#pragma unroll
    for (int c = 0; c < 4; c++) {
        f32x4 t = {0.f, 0.f, 0.f, 0.f};
        t = __builtin_amdgcn_mfma_f32_16x16x32_f16(a0, wf[(0 * 4 + c) * 64], t, 0, 0, 0);
        t = __builtin_amdgcn_mfma_f32_16x16x32_f16(a1, wf[(1 * 4 + c) * 64], t, 0, 0, 0);
        acc[c] = t;
    }

    int rowbase = tb + wv * 16 + lg * 4;
    float qv[4], dv[4];
    bool vld[4];
#pragma unroll
    for (int r = 0; r < 4; r++) {
        int row = rowbase + r;
        vld[r] = row < N;
        qv[r] = (HAS_AFF && vld[r]) ? q[row] : 0.f;
        dv[r] = (OM == 0 && vld[r]) ? dinv[row] : 0.f;
    }
    float sa[4], sq[4];
#pragma unroll
    for (int c = 0; c < 4; c++) { sa[c] = 0.f; sq[c] = 0.f; }

#pragma unroll
    for (int c = 0; c < 4; c++) {
        int col = c * 16 + l15;
        float bcol = bias[col];
        float ucol = HAS_AFF ? u[col] : 0.f;
        float Acol = (OM == 2) ? s0[col] : 0.f;
        float Ccol = (OM == 2) ? s1[col] : 0.f;
#pragma unroll
        for (int r = 0; r < 4; r++) {
            if (!vld[r]) continue;
            float o = acc[c][r] + bcol;
            if (HAS_AFF) o = fmaf(qv[r], ucol, o);
            float a = (MODE == 0) ? sigmoidf_(o)
                                  : ((MODE == 1) ? o : sigmoidf_(0.5f * o));
            int row = rowbase + r;
            if (OM == 0) {
                outh[(size_t)row * os + col] = f2h(a * dv[r]);
            } else if (OM == 1) {
                sa[c] += a;
                sq[c] += a * a;
            } else {
                outf[((size_t)row << 6) + col] = fmaf(a, Acol, Ccol);
            }
        }
    }

    if (OM == 1) {
        __shared__ float red[2][4][4][16];
#pragma unroll
        for (int c = 0; c < 4; c++) {
            sa[c] += __shfl_xor(sa[c], 16);
            sa[c] += __shfl_xor(sa[c], 32);
            sq[c] += __shfl_xor(sq[c], 16);
            sq[c] += __shfl_xor(sq[c], 32);
        }
        if (lg == 0) {
#pragma unroll
            for (int c = 0; c < 4; c++) {
                red[0][wv][c][l15] = sa[c];
                red[1][wv][c][l15] = sq[c];
            }
        }
        __syncthreads();
        if (wv == 0) {
            int c = lane >> 4, l = lane & 15;
            float t0 = red[0][0][c][l] + red[0][1][c][l] + red[0][2][c][l] + red[0][3][c][l];
            float t1 = red[1][0][c][l] + red[1][1][c][l] + red[1][2][c][l] + red[1][3][c][l];
            atomicAdd(&s0[lane], t0);
            atomicAdd(&s1[lane], t1);
        }
    }
}

// fused att1+str1 GEMM
__global__ __launch_bounds__(256) void gemm_dual(const ushort* __restrict__ zh,
                                                 const ushort* __restrict__ wfA,
                                                 const ushort* __restrict__ wfS,
                                                 const float* __restrict__ bA,
                                                 const float* __restrict__ bS,
                                                 const float* __restrict__ uA,
                                                 const float* __restrict__ uS,
                                                 const float* __restrict__ q,
                                                 const float* __restrict__ dinv,
                                                 ushort* __restrict__ outAB, int N) {
    int tid = threadIdx.x;
    int lane = tid & 63;
    int wv = tid >> 6;
    int l15 = lane & 15;
    int lg = lane >> 4;
    int tb = blockIdx.x * 64;

    const ushort* zrow = zh + ((size_t)(tb + wv * 16 + l15) << 6) + (lg << 3);
    f16x8 a0 = *reinterpret_cast<const f16x8*>(zrow);
    f16x8 a1 = *reinterpret_cast<const f16x8*>(zrow + 32);

    const f16x8* wa = reinterpret_cast<const f16x8*>(wfA) + lane;
    const f16x8* wsp = reinterpret_cast<const f16x8*>(wfS) + lane;

    f32x4 accA[4], accS[4];
#pragma unroll
    for (int c = 0; c < 4; c++) {
        f32x4 t = {0.f, 0.f, 0.f, 0.f};
        t = __builtin_amdgcn_mfma_f32_16x16x32_f16(a0, wa[(0 * 4 + c) * 64], t, 0, 0, 0);
        t = __builtin_amdgcn_mfma_f32_16x16x32_f16(a1, wa[(1 * 4 + c) * 64], t, 0, 0, 0);
        accA[c] = t;
        f32x4 t2 = {0.f, 0.f, 0.f, 0.f};
        t2 = __builtin_amdgcn_mfma_f32_16x16x32_f16(a0, wsp[(0 * 4 + c) * 64], t2, 0, 0, 0);
        t2 = __builtin_amdgcn_mfma_f32_16x16x32_f16(a1, wsp[(1 * 4 + c) * 64], t2, 0, 0, 0);
        accS[c] = t2;
    }

    int rowbase = tb + wv * 16 + lg * 4;
    float qv[4], dv[4];
    bool vld[4];
#pragma unroll
    for (int r = 0; r < 4; r++) {
        int row = rowbase + r;
        vld[r] = row < N;
        qv[r] = vld[r] ? q[row] : 0.f;
        dv[r] = vld[r] ? dinv[row] : 0.f;
    }
#pragma unroll
    for (int c = 0; c < 4; c++) {
        int col = c * 16 + l15;
        float bcA = bA[col], ucA = uA[col];
        float bcS = bS[col], ucS = uS[col];
#pragma unroll
        for (int r = 0; r < 4; r++) {
            if (!vld[r]) continue;
            int row = rowbase + r;
            float oA = fmaf(qv[r], ucA, accA[c][r] + bcA);
            float oS = fmaf(qv[r], ucS, accS[c][r] + bcS);
            float aA = sigmoidf_(oA);
            float aS = sigmoidf_(oS);
            outAB[((size_t)row << 7) + col] = f2h(aA * dv[r]);
            outAB[((size_t)row << 7) + 64 + col] = f2h(aS * dv[r]);
        }
    }
}

__global__ __launch_bounds__(256) void bn_apply_h(const ushort* __restrict__ actd,
                                                  const float* __restrict__ rdinv,
                                                  const float* __restrict__ A,
                                                  const float* __restrict__ C,
                                                  float* __restrict__ out, int N16) {
    int p = blockIdx.x * 256 + threadIdx.x;
    if (p >= N16) return;
    int n = p >> 4;
    int cb = (p & 15) * 4;
    float r = rdinv[n];
    ushort4 v = reinterpret_cast<const ushort4*>(actd)[p];
    float4 o;
    o.x = fmaf(h2f(v.x) * r, A[cb + 0], C[cb + 0]);
    o.y = fmaf(h2f(v.y) * r, A[cb + 1], C[cb + 1]);
    o.z = fmaf(h2f(v.z) * r, A[cb + 2], C[cb + 2]);
    o.w = fmaf(h2f(v.w) * r, A[cb + 3], C[cb + 3]);
    reinterpret_cast<float4*>(out)[p] = o;
}

// ---------------- launch ----------------

extern "C" void kernel_launch(void* const* d_in, const int* in_sizes, int n_in,
                              void* d_out, int out_size, void* d_ws, size_t ws_size,
                              hipStream_t stream) {
    const int N = in_sizes[0] / D;
    const int E = in_sizes[1] / 2;

    const float* x = (const float*)d_in[0];
    const int* ei = (const int*)d_in[1];
    const int* src_in = ei;
    const int* dst_in = ei + E;
    const float* encW = (const float*)d_in[3];
    const float* encb = (const float*)d_in[4];
    const float* encg = (const float*)d_in[5];
    const float* encbe = (const float*)d_in[6];
    const float* attW = (const float*)d_in[7];
    const float* attb = (const float*)d_in[8];
    const float* attg = (const float*)d_in[9];
    const float* attbe = (const float*)d_in[10];
    const float* strW = (const float*)d_in[11];
    const float* strb = (const float*)d_in[12];
    const float* strg = (const float*)d_in[13];
    const float* strbe = (const float*)d_in[14];

    const int NBd = (N + 1023) >> 10;
    const int NB2 = NS * NBd;
    int CAP = (E + NB2 - 1) / NB2;
    CAP = CAP + CAP / 4 + 128;
    CAP = (CAP + 255) & ~255;

    char* ws = (char*)d_ws;
    size_t off = 0;
    auto alloc = [&](size_t bytes) -> char* {
        char* p = ws + off;
        off += (bytes + 255) & ~(size_t)255;
        return p;
    };
    int* csr4 = (int*)alloc((size_t)NS * (N + 1) * 4);
    int* bcur = (int*)alloc(2048 * 4);
    int* boff = (int*)alloc(2048 * 4);
    float* dinv = (float*)alloc((size_t)N * 4);
    float* rdinv = (float*)alloc((size_t)N * 4);
    float* q = (float*)alloc((size_t)N * 4);
    float* stats = (float*)alloc(6 * 128 * 4);
    float* aff = (float*)alloc(6 * 128 * 4);
    float* ubuf = (float*)alloc(6 * 64 * 4);
    ushort* wf = (ushort*)alloc(6 * 4096 * 2);
    int* sorted = (int*)alloc((size_t)E * 4);
    ushort* zh = (ushort*)alloc((size_t)(N + 64) * 64 * 2);
    size_t binbytes = (size_t)NB2 * CAP * 4;
    size_t zabbytes = (size_t)(N + 64) * 128 * 2;
    char* region = alloc(binbytes > zabbytes ? binbytes : zabbytes);
    uint* bins = (uint*)region;
    ushort* zab = (ushort*)region;
    ushort* hA = (ushort*)alloc((size_t)N * 64 * 2);
    ushort* hB = (ushort*)alloc((size_t)N * 64 * 2);
    ushort* hAB = (ushort*)alloc((size_t)(N + 64) * 128 * 2);

    float* out_str = (float*)d_out;
    float* out_att = out_str + (size_t)N * D;
    float* out_enc = out_att + (size_t)N * D;

    hipMemsetAsync(bcur, 0, 2048 * 4, stream);
    hipMemsetAsync(stats, 0, 6 * 128 * 4, stream);

    int N16 = N * 16;
    int g16 = (N16 + 255) / 256;
    int gN = (N + 255) / 256;
    int gT = (N + 63) / 64;
    float invN = 1.0f / (float)N;

    float* A0 = aff + 0 * 128; float* C0 = A0 + 64;
    float* A1 = aff + 1 * 128; float* C1 = A1 + 64;
    float* A2 = aff + 2 * 128; float* C2 = A2 + 64;
    float* A3 = aff + 3 * 128; float* C3 = A3 + 64;
    float* A4 = aff + 4 * 128; float* C4 = A4 + 64;
    float* A5 = aff + 5 * 128; float* C5 = A5 + 64;
    ushort* wf0 = wf + 0 * 4096;
    ushort* wf1 = wf + 1 * 4096;
    ushort* wf2 = wf + 2 * 4096;
    ushort* wf3 = wf + 3 * 4096;
    ushort* wf4 = wf + 4 * 4096;
    ushort* wf5 = wf + 5 * 4096;

    // ---- CSR build (slice-major) ----
    bin_edges<<<(E + BCH - 1) / BCH, 256, 0, stream>>>(src_in, dst_in, bcur,
                                                       bins, CAP, NBd, NB2, E);
    scan2<<<1, 256, 0, stream>>>(bcur, boff, csr4, NBd, NB2, N, E);
    build_csr<<<NB2, 256, 0, stream>>>(bins, bcur, boff, csr4, sorted,
                                       CAP, NBd, N);
    deg_dinv<<<gN, 256, 0, stream>>>(csr4, dinv, rdinv, N);

    // ---- encoder layer 1 (q fused into first gather) ----
    prep_xd<<<g16, 256, 0, stream>>>(x, dinv, hA, N16);
    wprep<<<16, 256, 0, stream>>>(encW, wf0);
    agg_g<<<2048, 256, 0, stream>>>(hA, csr4, sorted, dinv, rdinv, zh,
                                    nullptr, nullptr, q, N, E);
    gemm_mfma<0, false, 0><<<gT, 256, 0, stream>>>(zh, 64, wf0, encb, nullptr,
                                                   q, dinv, hB, 64, nullptr,
                                                   nullptr, nullptr, N);
    // ---- encoder layer 2 ----
    agg_g<<<2048, 256, 0, stream>>>(hB, csr4, sorted, dinv, rdinv, zh,
                                    stats + 0, stats + 64, nullptr, N, E);
    layer_prep<<<1, 256, 0, stream>>>(stats + 0, stats + 64, encg, encbe,
                                      encW + 4096, A0, C0, ubuf + 0, wf1, invN);
    gemm_mfma<0, true, 0><<<gT, 256, 0, stream>>>(zh, 64, wf1, encb + 64, ubuf + 0,
                                                  q, dinv, hA, 64, nullptr,
                                                  nullptr, nullptr, N);
    // ---- z2 = Agg(x_enc act); enc2 stats ----
    agg_g<<<2048, 256, 0, stream>>>(hA, csr4, sorted, dinv, rdinv, zh,
                                    stats + 128, stats + 192, nullptr, N, E);
    layer_prep<<<1, 256, 0, stream>>>(stats + 128, stats + 192, encg + 64,
                                      encbe + 64, attW, A1, C1, ubuf + 64, wf2, invN);
    layer_prep<<<1, 256, 0, stream>>>(stats + 128, stats + 192, encg + 64,
                                      encbe + 64, strW, A1, C1, ubuf + 128, wf3, invN);
    bn_apply_h<<<g16, 256, 0, stream>>>(hA, rdinv, A1, C1, out_enc, N16);
    gemm_dual<<<gT, 256, 0, stream>>>(zh, wf2, wf3, attb, strb, ubuf + 64,
                                      ubuf + 128, q, dinv, hAB, N);
    // ---- fused att1|str1 gather (+ both stats) ----
    agg_dual<<<2048, 256, 0, stream>>>(hAB, csr4, sorted, dinv, rdinv, zab,
                                       stats + 256, stats + 320,
                                       stats + 512, stats + 576, N, E);
    // ---- attribute layer 2 (stats GEMM -> finalize -> apply GEMM) ----
    layer_prep<<<1, 256, 0, stream>>>(stats + 256, stats + 320, attg, attbe,
                                      attW + 4096, A2, C2, ubuf + 192, wf4, invN);
    gemm_mfma<1, true, 1><<<gT, 256, 0, stream>>>(zab, 128, wf4, attb + 64,
                                                  ubuf + 192, q, dinv, nullptr, 0,
                                                  nullptr, stats + 384, stats + 448, N);
    finalize_aff<<<1, 64, 0, stream>>>(stats + 384, stats + 448, attg + 64,
                                       attbe + 64, A3, C3, invN);
    gemm_mfma<1, true, 2><<<gT, 256, 0, stream>>>(zab, 128, wf4, attb + 64,
                                                  ubuf + 192, q, dinv, nullptr, 0,
                                                  out_att, A3, C3, N);
    // ---- structure layer 2 ----
    layer_prep<<<1, 256, 0, stream>>>(stats + 512, stats + 576, strg, strbe,
                                      strW + 4096, A4, C4, ubuf + 320, wf5, invN);
    gemm_mfma<2, true, 1><<<gT, 256, 0, stream>>>(zab + 64, 128, wf5, strb + 64,
                                                  ubuf + 320, q, dinv, nullptr, 0,
                                                  nullptr, stats + 640, stats + 704, N);
    finalize_aff<<<1, 64, 0, stream>>>(stats + 640, stats + 704, strg + 64,
                                       strbe + 64, A5, C5, invN);
    gemm_mfma<2, true, 2><<<gT, 256, 0, stream>>>(zab + 64, 128, wf5, strb + 64,
                                                  ubuf + 320, q, dinv, nullptr, 0,
                                                  out_str, A5, C5, N);
}

// Round 11
// 595.255 us; speedup vs baseline: 1.8115x; 1.8115x over previous
//
#include <hip/hip_runtime.h>

#define D 64
#define BCH 4096

typedef __attribute__((ext_vector_type(8))) _Float16 f16x8;
typedef __attribute__((ext_vector_type(4))) float f32x4;

__device__ __forceinline__ float sigmoidf_(float x) {
    return 1.0f / (1.0f + __expf(-x));
}
__device__ __forceinline__ float h2f(ushort u) {
    _Float16 h;
    __builtin_memcpy(&h, &u, 2);
    return (float)h;
}
__device__ __forceinline__ ushort f2h(float f) {
    _Float16 h = (_Float16)f;
    ushort u;
    __builtin_memcpy(&u, &h, 2);
    return u;
}
__device__ __forceinline__ float2 up2(uint v) {
    float2 r;
    r.x = h2f((ushort)(v & 0xffffu));
    r.y = h2f((ushort)(v >> 16));
    return r;
}

// ---------------- CSR build: bucket sort by dst, packed (src<<10 | dstlocal) ----------------

__global__ __launch_bounds__(256) void bin_edges(const int* __restrict__ src,
                                                 const int* __restrict__ dst,
                                                 int* __restrict__ bcur,
                                                 uint* __restrict__ bins,
                                                 int CAP, int E) {
    __shared__ uint lp[BCH];
    __shared__ unsigned char lb[BCH];
    __shared__ int hist[128], base[128];
    int t = threadIdx.x;
    int e0 = blockIdx.x * BCH;
    if (t < 128) hist[t] = 0;
    __syncthreads();
    for (int k = t; k < BCH; k += 256) {
        int e = e0 + k;
        uint p = 0xFFFFFFFFu;
        int b = 0;
        if (e < E) {
            int s_ = src[e];
            int d_ = dst[e];
            b = d_ >> 10;
            atomicAdd(&hist[b], 1);
            p = ((uint)s_ << 10) | (uint)(d_ & 1023);
        }
        lp[k] = p;
        lb[k] = (unsigned char)b;
    }
    __syncthreads();
    if (t < 128) {
        int c = hist[t];
        base[t] = (c > 0) ? atomicAdd(&bcur[t], c) : 0;
        hist[t] = 0;
    }
    __syncthreads();
    for (int k = t; k < BCH; k += 256) {
        uint p = lp[k];
        if (p != 0xFFFFFFFFu) {
            int b = lb[k];
            int pos = base[b] + atomicAdd(&hist[b], 1);
            bins[(size_t)b * CAP + pos] = p;
        }
    }
}

__global__ __launch_bounds__(128) void scan_nb(const int* __restrict__ bcur,
                                               int* __restrict__ boff,
                                               int* __restrict__ csr,
                                               int NB, int N, int E) {
    __shared__ int tmp[128];
    int t = threadIdx.x;
    int v = (t < NB) ? bcur[t] : 0;
    tmp[t] = v;
    __syncthreads();
    for (int o = 1; o < 128; o <<= 1) {
        int x = (t >= o) ? tmp[t - o] : 0;
        __syncthreads();
        tmp[t] += x;
        __syncthreads();
    }
    if (t < NB) boff[t] = tmp[t] - v;
    if (t == 0) csr[N] = E;
}

__global__ __launch_bounds__(256) void build_csr(const uint* __restrict__ bins,
                                                 const int* __restrict__ bcur,
                                                 const int* __restrict__ boff,
                                                 int* __restrict__ csr,
                                                 int* __restrict__ sorted,
                                                 float* __restrict__ dinv,
                                                 float* __restrict__ rdinv,
                                                 int CAP, int N) {
    __shared__ int hist[1024];
    __shared__ int part[256];
    int t = threadIdx.x;
    int b = blockIdx.x;
    int nb0 = b << 10;
    int cnt = bcur[b];
    int e0 = boff[b];
    const uint* bp = bins + (size_t)b * CAP;
    for (int k = t; k < 1024; k += 256) hist[k] = 0;
    __syncthreads();
    for (int k = t; k < cnt; k += 256) atomicAdd(&hist[bp[k] & 1023u], 1);
    __syncthreads();
    int v0 = hist[4 * t], v1 = hist[4 * t + 1], v2 = hist[4 * t + 2], v3 = hist[4 * t + 3];
    part[t] = v0 + v1 + v2 + v3;
    __syncthreads();
    for (int o = 1; o < 256; o <<= 1) {
        int x = (t >= o) ? part[t - o] : 0;
        __syncthreads();
        part[t] += x;
        __syncthreads();
    }
    int run = (t > 0) ? part[t - 1] : 0;
    int pre[4];
    pre[0] = run;
    pre[1] = run + v0;
    pre[2] = run + v0 + v1;
    pre[3] = run + v0 + v1 + v2;
    int deg[4] = {v0, v1, v2, v3};
    __syncthreads();
    hist[4 * t + 0] = e0 + pre[0];
    hist[4 * t + 1] = e0 + pre[1];
    hist[4 * t + 2] = e0 + pre[2];
    hist[4 * t + 3] = e0 + pre[3];
#pragma unroll
    for (int j = 0; j < 4; j++) {
        int node = nb0 + 4 * t + j;
        if (node < N) {
            csr[node] = e0 + pre[j];
            float c = (float)deg[j] + 1.0f;
            dinv[node] = rsqrtf(c);
            rdinv[node] = sqrtf(c);
        }
    }
    __syncthreads();
    for (int k = t; k < cnt; k += 256) {
        uint p = bp[k];
        int pos = atomicAdd(&hist[p & 1023u], 1);
        sorted[pos] = (int)(p >> 10);
    }
}

// ---------------- prep ----------------

__global__ __launch_bounds__(256) void prep_xd(const float* __restrict__ x,
                                               const float* __restrict__ dinv,
                                               ushort* __restrict__ actd, int N16) {
    int p = blockIdx.x * 256 + threadIdx.x;
    if (p >= N16) return;
    int n = p >> 4;
    float d = dinv[n];
    float4 v = reinterpret_cast<const float4*>(x)[p];
    ushort4 o;
    o.x = f2h(v.x * d);
    o.y = f2h(v.y * d);
    o.z = f2h(v.z * d);
    o.w = f2h(v.w * d);
    reinterpret_cast<ushort4*>(actd)[p] = o;
}

__global__ __launch_bounds__(256) void wprep(const float* __restrict__ W,
                                             ushort* __restrict__ wfrag) {
    int idx = blockIdx.x * 256 + threadIdx.x;
    if (idx >= 4096) return;
    int i = idx & 7;
    int lane = (idx >> 3) & 63;
    int hc = idx >> 9;
    int h = hc >> 2, c = hc & 3;
    int k = h * 32 + (lane >> 4) * 8 + i;
    int j = c * 16 + (lane & 15);
    wfrag[idx] = f2h(W[k * 64 + j]);
}

__global__ __launch_bounds__(256) void layer_prep(const float* __restrict__ ssum,
                                                  const float* __restrict__ sssq,
                                                  const float* __restrict__ gamma,
                                                  const float* __restrict__ beta,
                                                  const float* __restrict__ W,
                                                  float* __restrict__ A,
                                                  float* __restrict__ C,
                                                  float* __restrict__ u,
                                                  ushort* __restrict__ wfrag,
                                                  float invN) {
    __shared__ float As[64], Cs[64];
    int t = threadIdx.x;
    if (t < 64) {
        float m = ssum[t] * invN;
        float var = sssq[t] * invN - m * m;
        float rs = rsqrtf(var + 1e-4f);
        float a = rs * gamma[t];
        As[t] = a;
        A[t] = a;
        float c = fmaf(-m, a, beta[t]);
        Cs[t] = c;
        C[t] = c;
    }
    __syncthreads();
    if (t < 64) {
        float s = 0.f;
        for (int k = 0; k < 64; k++) s = fmaf(Cs[k], W[k * 64 + t], s);
        u[t] = s;
    }
    for (int idx = t; idx < 4096; idx += 256) {
        int i = idx & 7;
        int lane = (idx >> 3) & 63;
        int hc = idx >> 9;
        int h = hc >> 2, c = hc & 3;
        int k = h * 32 + (lane >> 4) * 8 + i;
        int j = c * 16 + (lane & 15);
        wfrag[idx] = f2h(W[k * 64 + j] * As[k]);
    }
}

__global__ __launch_bounds__(64) void finalize_aff(const float* __restrict__ ssum,
                                                   const float* __restrict__ sssq,
                                                   const float* __restrict__ gamma,
                                                   const float* __restrict__ beta,
                                                   float* __restrict__ A,
                                                   float* __restrict__ C, float invN) {
    int c = threadIdx.x;
    float m = ssum[c] * invN;
    float var = sssq[c] * invN - m * m;
    float rs = rsqrtf(var + 1e-4f);
    float a = rs * gamma[c];
    A[c] = a;
    C[c] = fmaf(-m, a, beta[c]);
}

// ---------------- aggregation ----------------

// 128B rows, feature = lane; two independent node streams per wave.
__global__ __launch_bounds__(256) void agg_g(const ushort* __restrict__ actd,
                                             const int* __restrict__ ptr,
                                             const int* __restrict__ srcs,
                                             const float* __restrict__ dinv,
                                             const float* __restrict__ rdinv,
                                             ushort* __restrict__ zh,
                                             float* __restrict__ ssum,
                                             float* __restrict__ sssq,
                                             float* __restrict__ qout, int N, int E) {
    __shared__ float red[2][4][64];
    int lane = threadIdx.x & 63;
    int wv = threadIdx.x >> 6;
    int l7 = lane & 7;
    int Em1 = E - 1;
    const bool do_stats = (ssum != nullptr);
    const bool do_q = (qout != nullptr);
    float ps = 0.f, pq = 0.f;
    int Nh = (N + 1) >> 1;
    for (int n0 = blockIdx.x * 4 + wv; n0 < Nh; n0 += gridDim.x * 4) {
        int nA = n0;
        int nB = n0 + Nh;
        bool hasB = nB < N;
        int sA = ptr[nA], eA = ptr[nA + 1];
        int sB = 0, eB = 0;
        if (hasB) { sB = ptr[nB]; eB = ptr[nB + 1]; }
        float selfA = h2f(actd[((size_t)nA << 6) + lane]);
        float accA = selfA;
        float dnA = dinv[nA];
        float accB = 0.f, dnB = 0.f;
        if (hasB) {
            float selfB = h2f(actd[((size_t)nB << 6) + lane]);
            accB = selfB;
            dnB = dinv[nB];
            if (do_stats) {
                float rb = rdinv[nB];
                float b = selfB * rb;
                ps += b;
                pq += b * b;
            }
        }
        if (do_stats) {
            float ra = rdinv[nA];
            float a = selfA * ra;
            ps += a;
            pq += a * a;
        }
        float qaA = 0.f, qaB = 0.f;
        int iA = sA, iB = sB;
        int idxA = srcs[min(iA + l7, Em1)];
        int idxB = hasB ? srcs[min(iB + l7, Em1)] : 0;
        while (iA + 8 <= eA || iB + 8 <= eB) {
            bool gA = iA + 8 <= eA;
            bool gB = iB + 8 <= eB;
            ushort ua[8], ub[8];
            if (gA) {
#pragma unroll
                for (int j = 0; j < 8; j++) {
                    int u = __builtin_amdgcn_readlane(idxA, j);
                    ua[j] = actd[((size_t)u << 6) + lane];
                    if (do_q) qaA += dinv[u];
                }
            }
            if (gB) {
#pragma unroll
                for (int j = 0; j < 8; j++) {
                    int u = __builtin_amdgcn_readlane(idxB, j);
                    ub[j] = actd[((size_t)u << 6) + lane];
                    if (do_q) qaB += dinv[u];
                }
            }
            int idxA2 = idxA, idxB2 = idxB;
            if (gA) idxA2 = srcs[min(iA + 8 + l7, Em1)];
            if (gB) idxB2 = srcs[min(iB + 8 + l7, Em1)];
            if (gA) {
                accA += ((h2f(ua[0]) + h2f(ua[1])) + (h2f(ua[2]) + h2f(ua[3]))) +
                        ((h2f(ua[4]) + h2f(ua[5])) + (h2f(ua[6]) + h2f(ua[7])));
                iA += 8;
                idxA = idxA2;
            }
            if (gB) {
                accB += ((h2f(ub[0]) + h2f(ub[1])) + (h2f(ub[2]) + h2f(ub[3]))) +
                        ((h2f(ub[4]) + h2f(ub[5])) + (h2f(ub[6]) + h2f(ub[7])));
                iB += 8;
                idxB = idxB2;
            }
        }
        if (iA < eA) {
#pragma unroll
            for (int j = 0; j < 8; j++) {
                int u = __builtin_amdgcn_readlane(idxA, j);
                float w = (iA + j < eA) ? 1.0f : 0.0f;
                float f = h2f(actd[((size_t)u << 6) + lane]);
                accA = fmaf(w, f, accA);
                if (do_q) qaA = fmaf(w, dinv[u], qaA);
            }
        }
        if (hasB && iB < eB) {
#pragma unroll
            for (int j = 0; j < 8; j++) {
                int u = __builtin_amdgcn_readlane(idxB, j);
                float w = (iB + j < eB) ? 1.0f : 0.0f;
                float f = h2f(actd[((size_t)u << 6) + lane]);
                accB = fmaf(w, f, accB);
                if (do_q) qaB = fmaf(w, dinv[u], qaB);
            }
        }
        if (do_q && lane == 0) {
            qout[nA] = dnA * (dnA + qaA);
            if (hasB) qout[nB] = dnB * (dnB + qaB);
        }
        zh[((size_t)nA << 6) + lane] = f2h(accA * dnA);
        if (hasB) zh[((size_t)nB << 6) + lane] = f2h(accB * dnB);
    }
    if (do_stats) {
        red[0][wv][lane] = ps;
        red[1][wv][lane] = pq;
        __syncthreads();
        if (wv == 0) {
            float t0 = red[0][0][lane] + red[0][1][lane] + red[0][2][lane] + red[0][3][lane];
            float t1 = red[1][0][lane] + red[1][1][lane] + red[1][2][lane] + red[1][3][lane];
            atomicAdd(&ssum[lane], t0);
            atomicAdd(&sssq[lane], t1);
        }
    }
}

// 256B rows (att|str interleaved), features 2*lane, 2*lane+1 (uint loads), single stream.
__global__ __launch_bounds__(256) void agg_dual(const ushort* __restrict__ ab,
                                                const int* __restrict__ ptr,
                                                const int* __restrict__ srcs,
                                                const float* __restrict__ dinv,
                                                const float* __restrict__ rdinv,
                                                ushort* __restrict__ zab,
                                                float* __restrict__ ssA,
                                                float* __restrict__ sqA,
                                                float* __restrict__ ssS,
                                                float* __restrict__ sqS,
                                                int N, int E) {
    __shared__ float red[2][4][128];
    int lane = threadIdx.x & 63;
    int wv = threadIdx.x >> 6;
    int l7 = lane & 7;
    int Em1 = E - 1;
    float2 ps = make_float2(0.f, 0.f), pq = make_float2(0.f, 0.f);
    for (int n = blockIdx.x * 4 + wv; n < N; n += gridDim.x * 4) {
        int s = ptr[n], e = ptr[n + 1];
        uint su = *reinterpret_cast<const uint*>(ab + ((size_t)n << 7) + (lane << 1));
        float2 acc = up2(su);
        {
            float r = rdinv[n];
            float ax = acc.x * r, ay = acc.y * r;
            ps.x += ax; ps.y += ay;
            pq.x += ax * ax; pq.y += ay * ay;
        }
        int i = s;
        int idx8 = srcs[min(i + l7, Em1)];
        while (i + 8 <= e) {
            int ni = i + 8;
            int nidx = srcs[min(ni + l7, Em1)];
#pragma unroll
            for (int j = 0; j < 8; j++) {
                int u = __builtin_amdgcn_readlane(idx8, j);
                uint v = *reinterpret_cast<const uint*>(ab + ((size_t)u << 7) + (lane << 1));
                float2 f = up2(v);
                acc.x += f.x;
                acc.y += f.y;
            }
            idx8 = nidx;
            i = ni;
        }
        if (i < e) {
#pragma unroll
            for (int j = 0; j < 8; j++) {
                int u = __builtin_amdgcn_readlane(idx8, j);
                uint v = *reinterpret_cast<const uint*>(ab + ((size_t)u << 7) + (lane << 1));
                float w = (i + j < e) ? 1.0f : 0.0f;
                float2 f = up2(v);
                acc.x = fmaf(w, f.x, acc.x);
                acc.y = fmaf(w, f.y, acc.y);
            }
        }
        float dn = dinv[n];
        uint pk = (uint)f2h(acc.x * dn) | ((uint)f2h(acc.y * dn) << 16);
        *reinterpret_cast<uint*>(zab + ((size_t)n << 7) + (lane << 1)) = pk;
    }
    red[0][wv][2 * lane + 0] = ps.x;
    red[0][wv][2 * lane + 1] = ps.y;
    red[1][wv][2 * lane + 0] = pq.x;
    red[1][wv][2 * lane + 1] = pq.y;
    __syncthreads();
    if (wv == 0) {
#pragma unroll
        for (int m0 = 0; m0 < 2; m0++) {
            int m = lane + m0 * 64;
            float t0 = red[0][0][m] + red[0][1][m] + red[0][2][m] + red[0][3][m];
            float t1 = red[1][0][m] + red[1][1][m] + red[1][2][m] + red[1][3][m];
            if (m < 64) {
                atomicAdd(&ssA[m], t0);
                atomicAdd(&sqA[m], t1);
            } else {
                atomicAdd(&ssS[m - 64], t0);
                atomicAdd(&sqS[m - 64], t1);
            }
        }
    }
}

// ---------------- MFMA GEMM ----------------
// OM: 0 = write fp16(act*dinv); 1 = stats + write fp16(act) raw.
template <int MODE, bool HAS_AFF, int OM>
__global__ __launch_bounds__(256) void gemm_mfma(const ushort* __restrict__ zh, int is,
                                                 const ushort* __restrict__ wfrag,
                                                 const float* __restrict__ bias,
                                                 const float* __restrict__ u,
                                                 const float* __restrict__ q,
                                                 const float* __restrict__ dinv,
                                                 ushort* __restrict__ outh, int os,
                                                 float* __restrict__ s0,
                                                 float* __restrict__ s1, int N) {
    int tid = threadIdx.x;
    int lane = tid & 63;
    int wv = tid >> 6;
    int l15 = lane & 15;
    int lg = lane >> 4;
    int tb = blockIdx.x * 64;

    const ushort* zrow = zh + (size_t)(tb + wv * 16 + l15) * is + (lg << 3);
    f16x8 a0 = *reinterpret_cast<const f16x8*>(zrow);
    f16x8 a1 = *reinterpret_cast<const f16x8*>(zrow + 32);

    const f16x8* wf = reinterpret_cast<const f16x8*>(wfrag) + lane;

    f32x4 acc[4];
#pragma unroll
    for (int c = 0; c < 4; c++) {
        f32x4 t = {0.f, 0.f, 0.f, 0.f};
        t = __builtin_amdgcn_mfma_f32_16x16x32_f16(a0, wf[(0 * 4 + c) * 64], t, 0, 0, 0);
        t = __builtin_amdgcn_mfma_f32_16x16x32_f16(a1, wf[(1 * 4 + c) * 64], t, 0, 0, 0);
        acc[c] = t;
    }

    int rowbase = tb + wv * 16 + lg * 4;
    float qv[4], dv[4];
    bool vld[4];
#pragma unroll
    for (int r = 0; r < 4; r++) {
        int row = rowbase + r;
        vld[r] = row < N;
        qv[r] = (HAS_AFF && vld[r]) ? q[row] : 0.f;
        dv[r] = (OM == 0 && vld[r]) ? dinv[row] : 0.f;
    }
    float sa[4], sq[4];
#pragma unroll
    for (int c = 0; c < 4; c++) { sa[c] = 0.f; sq[c] = 0.f; }

#pragma unroll
    for (int c = 0; c < 4; c++) {
        int col = c * 16 + l15;
        float bcol = bias[col];
        float ucol = HAS_AFF ? u[col] : 0.f;
#pragma unroll
        for (int r = 0; r < 4; r++) {
            if (!vld[r]) continue;
            float o = acc[c][r] + bcol;
            if (HAS_AFF) o = fmaf(qv[r], ucol, o);
            float a = (MODE == 0) ? sigmoidf_(o)
                                  : ((MODE == 1) ? o : sigmoidf_(0.5f * o));
            int row = rowbase + r;
            if (OM == 0) {
                outh[(size_t)row * os + col] = f2h(a * dv[r]);
            } else {
                outh[(size_t)row * os + col] = f2h(a);
                sa[c] += a;
                sq[c] += a * a;
            }
        }
    }

    if (OM == 1) {
        __shared__ float red[2][4][4][16];
#pragma unroll
        for (int c = 0; c < 4; c++) {
            sa[c] += __shfl_xor(sa[c], 16);
            sa[c] += __shfl_xor(sa[c], 32);
            sq[c] += __shfl_xor(sq[c], 16);
            sq[c] += __shfl_xor(sq[c], 32);
        }
        if (lg == 0) {
#pragma unroll
            for (int c = 0; c < 4; c++) {
                red[0][wv][c][l15] = sa[c];
                red[1][wv][c][l15] = sq[c];
            }
        }
        __syncthreads();
        if (wv == 0) {
            int c = lane >> 4, l = lane & 15;
            float t0 = red[0][0][c][l] + red[0][1][c][l] + red[0][2][c][l] + red[0][3][c][l];
            float t1 = red[1][0][c][l] + red[1][1][c][l] + red[1][2][c][l] + red[1][3][c][l];
            atomicAdd(&s0[lane], t0);
            atomicAdd(&s1[lane], t1);
        }
    }
}

// fused att1+str1 GEMM
__global__ __launch_bounds__(256) void gemm_dual(const ushort* __restrict__ zh,
                                                 const ushort* __restrict__ wfA,
                                                 const ushort* __restrict__ wfS,
                                                 const float* __restrict__ bA,
                                                 const float* __restrict__ bS,
                                                 const float* __restrict__ uA,
                                                 const float* __restrict__ uS,
                                                 const float* __restrict__ q,
                                                 const float* __restrict__ dinv,
                                                 ushort* __restrict__ outAB, int N) {
    int tid = threadIdx.x;
    int lane = tid & 63;
    int wv = tid >> 6;
    int l15 = lane & 15;
    int lg = lane >> 4;
    int tb = blockIdx.x * 64;

    const ushort* zrow = zh + ((size_t)(tb + wv * 16 + l15) << 6) + (lg << 3);
    f16x8 a0 = *reinterpret_cast<const f16x8*>(zrow);
    f16x8 a1 = *reinterpret_cast<const f16x8*>(zrow + 32);

    const f16x8* wa = reinterpret_cast<const f16x8*>(wfA) + lane;
    const f16x8* wsp = reinterpret_cast<const f16x8*>(wfS) + lane;

    f32x4 accA[4], accS[4];
#pragma unroll
    for (int c = 0; c < 4; c++) {
        f32x4 t = {0.f, 0.f, 0.f, 0.f};
        t = __builtin_amdgcn_mfma_f32_16x16x32_f16(a0, wa[(0 * 4 + c) * 64], t, 0, 0, 0);
        t = __builtin_amdgcn_mfma_f32_16x16x32_f16(a1, wa[(1 * 4 + c) * 64], t, 0, 0, 0);
        accA[c] = t;
        f32x4 t2 = {0.f, 0.f, 0.f, 0.f};
        t2 = __builtin_amdgcn_mfma_f32_16x16x32_f16(a0, wsp[(0 * 4 + c) * 64], t2, 0, 0, 0);
        t2 = __builtin_amdgcn_mfma_f32_16x16x32_f16(a1, wsp[(1 * 4 + c) * 64], t2, 0, 0, 0);
        accS[c] = t2;
    }

    int rowbase = tb + wv * 16 + lg * 4;
    float qv[4], dv[4];
    bool vld[4];
#pragma unroll
    for (int r = 0; r < 4; r++) {
        int row = rowbase + r;
        vld[r] = row < N;
        qv[r] = vld[r] ? q[row] : 0.f;
        dv[r] = vld[r] ? dinv[row] : 0.f;
    }
#pragma unroll
    for (int c = 0; c < 4; c++) {
        int col = c * 16 + l15;
        float bcA = bA[col], ucA = uA[col];
        float bcS = bS[col], ucS = uS[col];
#pragma unroll
        for (int r = 0; r < 4; r++) {
            if (!vld[r]) continue;
            int row = rowbase + r;
            float oA = fmaf(qv[r], ucA, accA[c][r] + bcA);
            float oS = fmaf(qv[r], ucS, accS[c][r] + bcS);
            float aA = sigmoidf_(oA);
            float aS = sigmoidf_(oS);
            outAB[((size_t)row << 7) + col] = f2h(aA * dv[r]);
            outAB[((size_t)row << 7) + 64 + col] = f2h(aS * dv[r]);
        }
    }
}

__global__ __launch_bounds__(256) void bn_apply_h(const ushort* __restrict__ actd,
                                                  const float* __restrict__ rdinv,
                                                  const float* __restrict__ A,
                                                  const float* __restrict__ C,
                                                  float* __restrict__ out, int N16) {
    int p = blockIdx.x * 256 + threadIdx.x;
    if (p >= N16) return;
    int n = p >> 4;
    int cb = (p & 15) * 4;
    float r = rdinv[n];
    ushort4 v = reinterpret_cast<const ushort4*>(actd)[p];
    float4 o;
    o.x = fmaf(h2f(v.x) * r, A[cb + 0], C[cb + 0]);
    o.y = fmaf(h2f(v.y) * r, A[cb + 1], C[cb + 1]);
    o.z = fmaf(h2f(v.z) * r, A[cb + 2], C[cb + 2]);
    o.w = fmaf(h2f(v.w) * r, A[cb + 3], C[cb + 3]);
    reinterpret_cast<float4*>(out)[p] = o;
}

// out = act(fp16) * A + C
__global__ __launch_bounds__(256) void bn_apply_hf(const ushort* __restrict__ acth,
                                                   const float* __restrict__ A,
                                                   const float* __restrict__ C,
                                                   float* __restrict__ out, int N16) {
    int p = blockIdx.x * 256 + threadIdx.x;
    if (p >= N16) return;
    int cb = (p & 15) * 4;
    ushort4 v = reinterpret_cast<const ushort4*>(acth)[p];
    float4 o;
    o.x = fmaf(h2f(v.x), A[cb + 0], C[cb + 0]);
    o.y = fmaf(h2f(v.y), A[cb + 1], C[cb + 1]);
    o.z = fmaf(h2f(v.z), A[cb + 2], C[cb + 2]);
    o.w = fmaf(h2f(v.w), A[cb + 3], C[cb + 3]);
    reinterpret_cast<float4*>(out)[p] = o;
}

// ---------------- launch ----------------

extern "C" void kernel_launch(void* const* d_in, const int* in_sizes, int n_in,
                              void* d_out, int out_size, void* d_ws, size_t ws_size,
                              hipStream_t stream) {
    const int N = in_sizes[0] / D;
    const int E = in_sizes[1] / 2;

    const float* x = (const float*)d_in[0];
    const int* ei = (const int*)d_in[1];
    const int* src_in = ei;
    const int* dst_in = ei + E;
    const float* encW = (const float*)d_in[3];
    const float* encb = (const float*)d_in[4];
    const float* encg = (const float*)d_in[5];
    const float* encbe = (const float*)d_in[6];
    const float* attW = (const float*)d_in[7];
    const float* attb = (const float*)d_in[8];
    const float* attg = (const float*)d_in[9];
    const float* attbe = (const float*)d_in[10];
    const float* strW = (const float*)d_in[11];
    const float* strb = (const float*)d_in[12];
    const float* strg = (const float*)d_in[13];
    const float* strbe = (const float*)d_in[14];

    const int NB = (N + 1023) >> 10;
    int CAP = (E + NB - 1) / NB;
    CAP = CAP + CAP / 8 + 256;
    CAP = (CAP + 255) & ~255;

    char* ws = (char*)d_ws;
    size_t off = 0;
    auto alloc = [&](size_t bytes) -> char* {
        char* p = ws + off;
        off += (bytes + 255) & ~(size_t)255;
        return p;
    };
    int* csr = (int*)alloc((size_t)(N + 1) * 4);
    int* bcur = (int*)alloc(128 * 4);
    int* boff = (int*)alloc(128 * 4);
    float* dinv = (float*)alloc((size_t)N * 4);
    float* rdinv = (float*)alloc((size_t)N * 4);
    float* q = (float*)alloc((size_t)N * 4);
    float* stats = (float*)alloc(6 * 128 * 4);
    float* aff = (float*)alloc(6 * 128 * 4);
    float* ubuf = (float*)alloc(6 * 64 * 4);
    ushort* wf = (ushort*)alloc(6 * 4096 * 2);
    int* sorted = (int*)alloc((size_t)E * 4);
    ushort* zh = (ushort*)alloc((size_t)(N + 64) * 64 * 2);
    size_t binbytes = (size_t)NB * CAP * 4;
    size_t zabbytes = (size_t)(N + 64) * 128 * 2;
    char* region = alloc(binbytes > zabbytes ? binbytes : zabbytes);
    uint* bins = (uint*)region;
    ushort* zab = (ushort*)region;
    ushort* hA = (ushort*)alloc((size_t)(N + 64) * 64 * 2);
    ushort* hB = (ushort*)alloc((size_t)(N + 64) * 64 * 2);
    ushort* hAB = (ushort*)alloc((size_t)(N + 64) * 128 * 2);

    float* out_str = (float*)d_out;
    float* out_att = out_str + (size_t)N * D;
    float* out_enc = out_att + (size_t)N * D;

    hipMemsetAsync(bcur, 0, 128 * 4, stream);
    hipMemsetAsync(stats, 0, 6 * 128 * 4, stream);

    int N16 = N * 16;
    int g16 = (N16 + 255) / 256;
    int gT = (N + 63) / 64;
    float invN = 1.0f / (float)N;

    float* A0 = aff + 0 * 128; float* C0 = A0 + 64;
    float* A1 = aff + 1 * 128; float* C1 = A1 + 64;
    float* A2 = aff + 2 * 128; float* C2 = A2 + 64;
    float* A3 = aff + 3 * 128; float* C3 = A3 + 64;
    float* A4 = aff + 4 * 128; float* C4 = A4 + 64;
    float* A5 = aff + 5 * 128; float* C5 = A5 + 64;
    ushort* wf0 = wf + 0 * 4096;
    ushort* wf1 = wf + 1 * 4096;
    ushort* wf2 = wf + 2 * 4096;
    ushort* wf3 = wf + 3 * 4096;
    ushort* wf4 = wf + 4 * 4096;
    ushort* wf5 = wf + 5 * 4096;

    // ---- CSR build ----
    bin_edges<<<(E + BCH - 1) / BCH, 256, 0, stream>>>(src_in, dst_in, bcur,
                                                       bins, CAP, E);
    scan_nb<<<1, 128, 0, stream>>>(bcur, boff, csr, NB, N, E);
    build_csr<<<NB, 256, 0, stream>>>(bins, bcur, boff, csr, sorted,
                                      dinv, rdinv, CAP, N);

    // ---- encoder layer 1 (q fused into first gather) ----
    prep_xd<<<g16, 256, 0, stream>>>(x, dinv, hA, N16);
    wprep<<<16, 256, 0, stream>>>(encW, wf0);
    agg_g<<<2048, 256, 0, stream>>>(hA, csr, sorted, dinv, rdinv, zh,
                                    nullptr, nullptr, q, N, E);
    gemm_mfma<0, false, 0><<<gT, 256, 0, stream>>>(zh, 64, wf0, encb, nullptr,
                                                   q, dinv, hB, 64,
                                                   nullptr, nullptr, N);
    // ---- encoder layer 2 ----
    agg_g<<<2048, 256, 0, stream>>>(hB, csr, sorted, dinv, rdinv, zh,
                                    stats + 0, stats + 64, nullptr, N, E);
    layer_prep<<<1, 256, 0, stream>>>(stats + 0, stats + 64, encg, encbe,
                                      encW + 4096, A0, C0, ubuf + 0, wf1, invN);
    gemm_mfma<0, true, 0><<<gT, 256, 0, stream>>>(zh, 64, wf1, encb + 64, ubuf + 0,
                                                  q, dinv, hA, 64,
                                                  nullptr, nullptr, N);
    // ---- z2 = Agg(x_enc act); enc2 stats ----
    agg_g<<<2048, 256, 0, stream>>>(hA, csr, sorted, dinv, rdinv, zh,
                                    stats + 128, stats + 192, nullptr, N, E);
    layer_prep<<<1, 256, 0, stream>>>(stats + 128, stats + 192, encg + 64,
                                      encbe + 64, attW, A1, C1, ubuf + 64, wf2, invN);
    layer_prep<<<1, 256, 0, stream>>>(stats + 128, stats + 192, encg + 64,
                                      encbe + 64, strW, A1, C1, ubuf + 128, wf3, invN);
    bn_apply_h<<<g16, 256, 0, stream>>>(hA, rdinv, A1, C1, out_enc, N16);
    gemm_dual<<<gT, 256, 0, stream>>>(zh, wf2, wf3, attb, strb, ubuf + 64,
                                      ubuf + 128, q, dinv, hAB, N);
    // ---- fused att1|str1 gather (+ both stats) ----
    agg_dual<<<2048, 256, 0, stream>>>(hAB, csr, sorted, dinv, rdinv, zab,
                                       stats + 256, stats + 320,
                                       stats + 512, stats + 576, N, E);
    // ---- attribute layer 2 (stats+act GEMM -> finalize -> fp16 apply) ----
    layer_prep<<<1, 256, 0, stream>>>(stats + 256, stats + 320, attg, attbe,
                                      attW + 4096, A2, C2, ubuf + 192, wf4, invN);
    gemm_mfma<1, true, 1><<<gT, 256, 0, stream>>>(zab, 128, wf4, attb + 64,
                                                  ubuf + 192, q, dinv, hAB, 64,
                                                  stats + 384, stats + 448, N);
    finalize_aff<<<1, 64, 0, stream>>>(stats + 384, stats + 448, attg + 64,
                                       attbe + 64, A3, C3, invN);
    bn_apply_hf<<<g16, 256, 0, stream>>>(hAB, A3, C3, out_att, N16);
    // ---- structure layer 2 ----
    layer_prep<<<1, 256, 0, stream>>>(stats + 512, stats + 576, strg, strbe,
                                      strW + 4096, A4, C4, ubuf + 320, wf5, invN);
    gemm_mfma<2, true, 1><<<gT, 256, 0, stream>>>(zab + 64, 128, wf5, strb + 64,
                                                  ubuf + 320, q, dinv, hA, 64,
                                                  stats + 640, stats + 704, N);
    finalize_aff<<<1, 64, 0, stream>>>(stats + 640, stats + 704, strg + 64,
                                       strbe + 64, A5, C5, invN);
    bn_apply_hf<<<g16, 256, 0, stream>>>(hA, A5, C5, out_str, N16);
}

// Round 12
// 585.689 us; speedup vs baseline: 1.8411x; 1.0163x over previous
//
#include <hip/hip_runtime.h>

#define D 64
#define BCH 4096

typedef __attribute__((ext_vector_type(8))) _Float16 f16x8;
typedef __attribute__((ext_vector_type(4))) float f32x4;

__device__ __forceinline__ float sigmoidf_(float x) {
    return 1.0f / (1.0f + __expf(-x));
}
__device__ __forceinline__ float h2f(ushort u) {
    _Float16 h;
    __builtin_memcpy(&h, &u, 2);
    return (float)h;
}
__device__ __forceinline__ ushort f2h(float f) {
    _Float16 h = (_Float16)f;
    ushort u;
    __builtin_memcpy(&u, &h, 2);
    return u;
}
__device__ __forceinline__ float2 up2(uint v) {
    float2 r;
    r.x = h2f((ushort)(v & 0xffffu));
    r.y = h2f((ushort)(v >> 16));
    return r;
}

// ---------------- CSR build: bucket sort by dst, packed (src<<10 | dstlocal) ----------------

__global__ __launch_bounds__(256) void bin_edges(const int* __restrict__ src,
                                                 const int* __restrict__ dst,
                                                 int* __restrict__ bcur,
                                                 uint* __restrict__ bins,
                                                 int CAP, int E) {
    __shared__ uint lp[BCH];
    __shared__ unsigned char lb[BCH];
    __shared__ int hist[128], base[128];
    int t = threadIdx.x;
    int e0 = blockIdx.x * BCH;
    if (t < 128) hist[t] = 0;
    __syncthreads();
    for (int k = t; k < BCH; k += 256) {
        int e = e0 + k;
        uint p = 0xFFFFFFFFu;
        int b = 0;
        if (e < E) {
            int s_ = src[e];
            int d_ = dst[e];
            b = d_ >> 10;
            atomicAdd(&hist[b], 1);
            p = ((uint)s_ << 10) | (uint)(d_ & 1023);
        }
        lp[k] = p;
        lb[k] = (unsigned char)b;
    }
    __syncthreads();
    if (t < 128) {
        int c = hist[t];
        base[t] = (c > 0) ? atomicAdd(&bcur[t], c) : 0;
        hist[t] = 0;
    }
    __syncthreads();
    for (int k = t; k < BCH; k += 256) {
        uint p = lp[k];
        if (p != 0xFFFFFFFFu) {
            int b = lb[k];
            int pos = base[b] + atomicAdd(&hist[b], 1);
            bins[(size_t)b * CAP + pos] = p;
        }
    }
}

__global__ __launch_bounds__(128) void scan_nb(const int* __restrict__ bcur,
                                               int* __restrict__ boff,
                                               int* __restrict__ csr,
                                               int NB, int N, int E) {
    __shared__ int tmp[128];
    int t = threadIdx.x;
    int v = (t < NB) ? bcur[t] : 0;
    tmp[t] = v;
    __syncthreads();
    for (int o = 1; o < 128; o <<= 1) {
        int x = (t >= o) ? tmp[t - o] : 0;
        __syncthreads();
        tmp[t] += x;
        __syncthreads();
    }
    if (t < NB) boff[t] = tmp[t] - v;
    if (t == 0) csr[N] = E;
}

__global__ __launch_bounds__(256) void build_csr(const uint* __restrict__ bins,
                                                 const int* __restrict__ bcur,
                                                 const int* __restrict__ boff,
                                                 int* __restrict__ csr,
                                                 int* __restrict__ sorted,
                                                 float* __restrict__ dinv,
                                                 float* __restrict__ rdinv,
                                                 int CAP, int N) {
    __shared__ int hist[1024];
    __shared__ int part[256];
    int t = threadIdx.x;
    int b = blockIdx.x;
    int nb0 = b << 10;
    int cnt = bcur[b];
    int e0 = boff[b];
    const uint* bp = bins + (size_t)b * CAP;
    for (int k = t; k < 1024; k += 256) hist[k] = 0;
    __syncthreads();
    for (int k = t; k < cnt; k += 256) atomicAdd(&hist[bp[k] & 1023u], 1);
    __syncthreads();
    int v0 = hist[4 * t], v1 = hist[4 * t + 1], v2 = hist[4 * t + 2], v3 = hist[4 * t + 3];
    part[t] = v0 + v1 + v2 + v3;
    __syncthreads();
    for (int o = 1; o < 256; o <<= 1) {
        int x = (t >= o) ? part[t - o] : 0;
        __syncthreads();
        part[t] += x;
        __syncthreads();
    }
    int run = (t > 0) ? part[t - 1] : 0;
    int pre[4];
    pre[0] = run;
    pre[1] = run + v0;
    pre[2] = run + v0 + v1;
    pre[3] = run + v0 + v1 + v2;
    int deg[4] = {v0, v1, v2, v3};
    __syncthreads();
    hist[4 * t + 0] = e0 + pre[0];
    hist[4 * t + 1] = e0 + pre[1];
    hist[4 * t + 2] = e0 + pre[2];
    hist[4 * t + 3] = e0 + pre[3];
#pragma unroll
    for (int j = 0; j < 4; j++) {
        int node = nb0 + 4 * t + j;
        if (node < N) {
            csr[node] = e0 + pre[j];
            float c = (float)deg[j] + 1.0f;
            dinv[node] = rsqrtf(c);
            rdinv[node] = sqrtf(c);
        }
    }
    __syncthreads();
    for (int k = t; k < cnt; k += 256) {
        uint p = bp[k];
        int pos = atomicAdd(&hist[p & 1023u], 1);
        sorted[pos] = (int)(p >> 10);
    }
}

// ---------------- prep ----------------

__global__ __launch_bounds__(256) void prep_xd(const float* __restrict__ x,
                                               const float* __restrict__ dinv,
                                               ushort* __restrict__ actd, int N16) {
    int p = blockIdx.x * 256 + threadIdx.x;
    if (p >= N16) return;
    int n = p >> 4;
    float d = dinv[n];
    float4 v = reinterpret_cast<const float4*>(x)[p];
    ushort4 o;
    o.x = f2h(v.x * d);
    o.y = f2h(v.y * d);
    o.z = f2h(v.z * d);
    o.w = f2h(v.w * d);
    reinterpret_cast<ushort4*>(actd)[p] = o;
}

// all six W matrices -> fp16 B-fragments (no affine folding)
__global__ __launch_bounds__(256) void wprep6(const float* __restrict__ encW,
                                              const float* __restrict__ attW,
                                              const float* __restrict__ strW,
                                              ushort* __restrict__ wf) {
    int w = blockIdx.x >> 4;  // 0..5
    int idx = (blockIdx.x & 15) * 256 + threadIdx.x;
    const float* W = (w == 0) ? encW
                   : (w == 1) ? (encW + 4096)
                   : (w == 2) ? attW
                   : (w == 3) ? strW
                   : (w == 4) ? (attW + 4096)
                              : (strW + 4096);
    int i = idx & 7;
    int lane = (idx >> 3) & 63;
    int hc = idx >> 9;
    int h = hc >> 2, c = hc & 3;
    int k = h * 32 + (lane >> 4) * 8 + i;
    int j = c * 16 + (lane & 15);
    wf[w * 4096 + idx] = f2h(W[k * 64 + j]);
}

// ---------------- aggregation (unchanged from R11) ----------------

__global__ __launch_bounds__(256) void agg_g(const ushort* __restrict__ actd,
                                             const int* __restrict__ ptr,
                                             const int* __restrict__ srcs,
                                             const float* __restrict__ dinv,
                                             const float* __restrict__ rdinv,
                                             ushort* __restrict__ zh,
                                             float* __restrict__ ssum,
                                             float* __restrict__ sssq,
                                             float* __restrict__ qout, int N, int E) {
    __shared__ float red[2][4][64];
    int lane = threadIdx.x & 63;
    int wv = threadIdx.x >> 6;
    int l7 = lane & 7;
    int Em1 = E - 1;
    const bool do_stats = (ssum != nullptr);
    const bool do_q = (qout != nullptr);
    float ps = 0.f, pq = 0.f;
    int Nh = (N + 1) >> 1;
    for (int n0 = blockIdx.x * 4 + wv; n0 < Nh; n0 += gridDim.x * 4) {
        int nA = n0;
        int nB = n0 + Nh;
        bool hasB = nB < N;
        int sA = ptr[nA], eA = ptr[nA + 1];
        int sB = 0, eB = 0;
        if (hasB) { sB = ptr[nB]; eB = ptr[nB + 1]; }
        float selfA = h2f(actd[((size_t)nA << 6) + lane]);
        float accA = selfA;
        float dnA = dinv[nA];
        float accB = 0.f, dnB = 0.f;
        if (hasB) {
            float selfB = h2f(actd[((size_t)nB << 6) + lane]);
            accB = selfB;
            dnB = dinv[nB];
            if (do_stats) {
                float rb = rdinv[nB];
                float b = selfB * rb;
                ps += b;
                pq += b * b;
            }
        }
        if (do_stats) {
            float ra = rdinv[nA];
            float a = selfA * ra;
            ps += a;
            pq += a * a;
        }
        float qaA = 0.f, qaB = 0.f;
        int iA = sA, iB = sB;
        int idxA = srcs[min(iA + l7, Em1)];
        int idxB = hasB ? srcs[min(iB + l7, Em1)] : 0;
        while (iA + 8 <= eA || iB + 8 <= eB) {
            bool gA = iA + 8 <= eA;
            bool gB = iB + 8 <= eB;
            ushort ua[8], ub[8];
            if (gA) {
#pragma unroll
                for (int j = 0; j < 8; j++) {
                    int u = __builtin_amdgcn_readlane(idxA, j);
                    ua[j] = actd[((size_t)u << 6) + lane];
                    if (do_q) qaA += dinv[u];
                }
            }
            if (gB) {
#pragma unroll
                for (int j = 0; j < 8; j++) {
                    int u = __builtin_amdgcn_readlane(idxB, j);
                    ub[j] = actd[((size_t)u << 6) + lane];
                    if (do_q) qaB += dinv[u];
                }
            }
            int idxA2 = idxA, idxB2 = idxB;
            if (gA) idxA2 = srcs[min(iA + 8 + l7, Em1)];
            if (gB) idxB2 = srcs[min(iB + 8 + l7, Em1)];
            if (gA) {
                accA += ((h2f(ua[0]) + h2f(ua[1])) + (h2f(ua[2]) + h2f(ua[3]))) +
                        ((h2f(ua[4]) + h2f(ua[5])) + (h2f(ua[6]) + h2f(ua[7])));
                iA += 8;
                idxA = idxA2;
            }
            if (gB) {
                accB += ((h2f(ub[0]) + h2f(ub[1])) + (h2f(ub[2]) + h2f(ub[3]))) +
                        ((h2f(ub[4]) + h2f(ub[5])) + (h2f(ub[6]) + h2f(ub[7])));
                iB += 8;
                idxB = idxB2;
            }
        }
        if (iA < eA) {
#pragma unroll
            for (int j = 0; j < 8; j++) {
                int u = __builtin_amdgcn_readlane(idxA, j);
                float w = (iA + j < eA) ? 1.0f : 0.0f;
                float f = h2f(actd[((size_t)u << 6) + lane]);
                accA = fmaf(w, f, accA);
                if (do_q) qaA = fmaf(w, dinv[u], qaA);
            }
        }
        if (hasB && iB < eB) {
#pragma unroll
            for (int j = 0; j < 8; j++) {
                int u = __builtin_amdgcn_readlane(idxB, j);
                float w = (iB + j < eB) ? 1.0f : 0.0f;
                float f = h2f(actd[((size_t)u << 6) + lane]);
                accB = fmaf(w, f, accB);
                if (do_q) qaB = fmaf(w, dinv[u], qaB);
            }
        }
        if (do_q && lane == 0) {
            qout[nA] = dnA * (dnA + qaA);
            if (hasB) qout[nB] = dnB * (dnB + qaB);
        }
        zh[((size_t)nA << 6) + lane] = f2h(accA * dnA);
        if (hasB) zh[((size_t)nB << 6) + lane] = f2h(accB * dnB);
    }
    if (do_stats) {
        red[0][wv][lane] = ps;
        red[1][wv][lane] = pq;
        __syncthreads();
        if (wv == 0) {
            float t0 = red[0][0][lane] + red[0][1][lane] + red[0][2][lane] + red[0][3][lane];
            float t1 = red[1][0][lane] + red[1][1][lane] + red[1][2][lane] + red[1][3][lane];
            atomicAdd(&ssum[lane], t0);
            atomicAdd(&sssq[lane], t1);
        }
    }
}

__global__ __launch_bounds__(256) void agg_dual(const ushort* __restrict__ ab,
                                                const int* __restrict__ ptr,
                                                const int* __restrict__ srcs,
                                                const float* __restrict__ dinv,
                                                const float* __restrict__ rdinv,
                                                ushort* __restrict__ zab,
                                                float* __restrict__ ssA,
                                                float* __restrict__ sqA,
                                                float* __restrict__ ssS,
                                                float* __restrict__ sqS,
                                                int N, int E) {
    __shared__ float red[2][4][128];
    int lane = threadIdx.x & 63;
    int wv = threadIdx.x >> 6;
    int l7 = lane & 7;
    int Em1 = E - 1;
    float2 ps = make_float2(0.f, 0.f), pq = make_float2(0.f, 0.f);
    for (int n = blockIdx.x * 4 + wv; n < N; n += gridDim.x * 4) {
        int s = ptr[n], e = ptr[n + 1];
        uint su = *reinterpret_cast<const uint*>(ab + ((size_t)n << 7) + (lane << 1));
        float2 acc = up2(su);
        {
            float r = rdinv[n];
            float ax = acc.x * r, ay = acc.y * r;
            ps.x += ax; ps.y += ay;
            pq.x += ax * ax; pq.y += ay * ay;
        }
        int i = s;
        int idx8 = srcs[min(i + l7, Em1)];
        while (i + 8 <= e) {
            int ni = i + 8;
            int nidx = srcs[min(ni + l7, Em1)];
#pragma unroll
            for (int j = 0; j < 8; j++) {
                int u = __builtin_amdgcn_readlane(idx8, j);
                uint v = *reinterpret_cast<const uint*>(ab + ((size_t)u << 7) + (lane << 1));
                float2 f = up2(v);
                acc.x += f.x;
                acc.y += f.y;
            }
            idx8 = nidx;
            i = ni;
        }
        if (i < e) {
#pragma unroll
            for (int j = 0; j < 8; j++) {
                int u = __builtin_amdgcn_readlane(idx8, j);
                uint v = *reinterpret_cast<const uint*>(ab + ((size_t)u << 7) + (lane << 1));
                float w = (i + j < e) ? 1.0f : 0.0f;
                float2 f = up2(v);
                acc.x = fmaf(w, f.x, acc.x);
                acc.y = fmaf(w, f.y, acc.y);
            }
        }
        float dn = dinv[n];
        uint pk = (uint)f2h(acc.x * dn) | ((uint)f2h(acc.y * dn) << 16);
        *reinterpret_cast<uint*>(zab + ((size_t)n << 7) + (lane << 1)) = pk;
    }
    red[0][wv][2 * lane + 0] = ps.x;
    red[0][wv][2 * lane + 1] = ps.y;
    red[1][wv][2 * lane + 0] = pq.x;
    red[1][wv][2 * lane + 1] = pq.y;
    __syncthreads();
    if (wv == 0) {
#pragma unroll
        for (int m0 = 0; m0 < 2; m0++) {
            int m = lane + m0 * 64;
            float t0 = red[0][0][m] + red[0][1][m] + red[0][2][m] + red[0][3][m];
            float t1 = red[1][0][m] + red[1][1][m] + red[1][2][m] + red[1][3][m];
            if (m < 64) {
                atomicAdd(&ssA[m], t0);
                atomicAdd(&sqA[m], t1);
            } else {
                atomicAdd(&ssS[m - 64], t0);
                atomicAdd(&sqS[m - 64], t1);
            }
        }
    }
}

// ---------------- MFMA GEMM (self-contained affine prologue) ----------------
// HAS_AFF: compute A/C/u from input stats per block; scale A-frags by fp16 A.
// OM: 0 = write fp16(act*dinv); 1 = stats out + write fp16(act) raw.
template <int MODE, bool HAS_AFF, int OM>
__global__ __launch_bounds__(256) void gemm_mfma(const ushort* __restrict__ zh, int is,
                                                 const ushort* __restrict__ wfrag,
                                                 const float* __restrict__ st0,
                                                 const float* __restrict__ st1,
                                                 const float* __restrict__ gamma,
                                                 const float* __restrict__ beta,
                                                 const float* __restrict__ Wf32,
                                                 const float* __restrict__ bias,
                                                 const float* __restrict__ q,
                                                 const float* __restrict__ dinv,
                                                 ushort* __restrict__ outh, int os,
                                                 float* __restrict__ so0,
                                                 float* __restrict__ so1,
                                                 float invN, int N) {
    __shared__ float Cs[64], us[64];
    __shared__ ushort aph[64];
    int tid = threadIdx.x;
    int lane = tid & 63;
    int wv = tid >> 6;
    int l15 = lane & 15;
    int lg = lane >> 4;
    int tb = blockIdx.x * 64;

    if (HAS_AFF) {
        if (tid < 64) {
            float m = st0[tid] * invN;
            float var = st1[tid] * invN - m * m;
            float a = rsqrtf(var + 1e-4f) * gamma[tid];
            Cs[tid] = fmaf(-m, a, beta[tid]);
            aph[tid] = f2h(a);
        }
        __syncthreads();
        if (tid < 64) {
            float s = 0.f;
#pragma unroll
            for (int k = 0; k < 64; k++) s = fmaf(Cs[k], Wf32[k * 64 + tid], s);
            us[tid] = s;
        }
        __syncthreads();
    }

    const ushort* zrow = zh + (size_t)(tb + wv * 16 + l15) * is + (lg << 3);
    f16x8 a0 = *reinterpret_cast<const f16x8*>(zrow);
    f16x8 a1 = *reinterpret_cast<const f16x8*>(zrow + 32);
    if (HAS_AFF) {
        const f16x8* aps = reinterpret_cast<const f16x8*>(aph);
        a0 = a0 * aps[lg];
        a1 = a1 * aps[4 + lg];
    }

    const f16x8* wf = reinterpret_cast<const f16x8*>(wfrag) + lane;

    f32x4 acc[4];
#pragma unroll
    for (int c = 0; c < 4; c++) {
        f32x4 t = {0.f, 0.f, 0.f, 0.f};
        t = __builtin_amdgcn_mfma_f32_16x16x32_f16(a0, wf[(0 * 4 + c) * 64], t, 0, 0, 0);
        t = __builtin_amdgcn_mfma_f32_16x16x32_f16(a1, wf[(1 * 4 + c) * 64], t, 0, 0, 0);
        acc[c] = t;
    }

    int rowbase = tb + wv * 16 + lg * 4;
    float qv[4], dv[4];
    bool vld[4];
#pragma unroll
    for (int r = 0; r < 4; r++) {
        int row = rowbase + r;
        vld[r] = row < N;
        qv[r] = (HAS_AFF && vld[r]) ? q[row] : 0.f;
        dv[r] = (OM == 0 && vld[r]) ? dinv[row] : 0.f;
    }
    float sa[4], sq[4];
#pragma unroll
    for (int c = 0; c < 4; c++) { sa[c] = 0.f; sq[c] = 0.f; }

#pragma unroll
    for (int c = 0; c < 4; c++) {
        int col = c * 16 + l15;
        float bcol = bias[col];
        float ucol = HAS_AFF ? us[col] : 0.f;
#pragma unroll
        for (int r = 0; r < 4; r++) {
            if (!vld[r]) continue;
            float o = acc[c][r] + bcol;
            if (HAS_AFF) o = fmaf(qv[r], ucol, o);
            float a = (MODE == 0) ? sigmoidf_(o)
                                  : ((MODE == 1) ? o : sigmoidf_(0.5f * o));
            int row = rowbase + r;
            if (OM == 0) {
                outh[(size_t)row * os + col] = f2h(a * dv[r]);
            } else {
                outh[(size_t)row * os + col] = f2h(a);
                sa[c] += a;
                sq[c] += a * a;
            }
        }
    }

    if (OM == 1) {
        __shared__ float red[2][4][4][16];
#pragma unroll
        for (int c = 0; c < 4; c++) {
            sa[c] += __shfl_xor(sa[c], 16);
            sa[c] += __shfl_xor(sa[c], 32);
            sq[c] += __shfl_xor(sq[c], 16);
            sq[c] += __shfl_xor(sq[c], 32);
        }
        if (lg == 0) {
#pragma unroll
            for (int c = 0; c < 4; c++) {
                red[0][wv][c][l15] = sa[c];
                red[1][wv][c][l15] = sq[c];
            }
        }
        __syncthreads();
        if (wv == 0) {
            int c = lane >> 4, l = lane & 15;
            float t0 = red[0][0][c][l] + red[0][1][c][l] + red[0][2][c][l] + red[0][3][c][l];
            float t1 = red[1][0][c][l] + red[1][1][c][l] + red[1][2][c][l] + red[1][3][c][l];
            atomicAdd(&so0[lane], t0);
            atomicAdd(&so1[lane], t1);
        }
    }
}

// fused att1+str1 GEMM with self-contained prologue (enc2 affine + uA + uS)
__global__ __launch_bounds__(256) void gemm_dual(const ushort* __restrict__ zh,
                                                 const ushort* __restrict__ wfA,
                                                 const ushort* __restrict__ wfS,
                                                 const float* __restrict__ st0,
                                                 const float* __restrict__ st1,
                                                 const float* __restrict__ gamma,
                                                 const float* __restrict__ beta,
                                                 const float* __restrict__ WAf32,
                                                 const float* __restrict__ WSf32,
                                                 const float* __restrict__ bA,
                                                 const float* __restrict__ bS,
                                                 const float* __restrict__ q,
                                                 const float* __restrict__ dinv,
                                                 ushort* __restrict__ outAB,
                                                 float invN, int N) {
    __shared__ float Cs[64], usA[64], usS[64];
    __shared__ ushort aph[64];
    int tid = threadIdx.x;
    int lane = tid & 63;
    int wv = tid >> 6;
    int l15 = lane & 15;
    int lg = lane >> 4;
    int tb = blockIdx.x * 64;

    if (tid < 64) {
        float m = st0[tid] * invN;
        float var = st1[tid] * invN - m * m;
        float a = rsqrtf(var + 1e-4f) * gamma[tid];
        Cs[tid] = fmaf(-m, a, beta[tid]);
        aph[tid] = f2h(a);
    }
    __syncthreads();
    if (tid < 64) {
        float s = 0.f;
#pragma unroll
        for (int k = 0; k < 64; k++) s = fmaf(Cs[k], WAf32[k * 64 + tid], s);
        usA[tid] = s;
    } else if (tid < 128) {
        int j = tid - 64;
        float s = 0.f;
#pragma unroll
        for (int k = 0; k < 64; k++) s = fmaf(Cs[k], WSf32[k * 64 + j], s);
        usS[j] = s;
    }
    __syncthreads();

    const ushort* zrow = zh + ((size_t)(tb + wv * 16 + l15) << 6) + (lg << 3);
    f16x8 a0 = *reinterpret_cast<const f16x8*>(zrow);
    f16x8 a1 = *reinterpret_cast<const f16x8*>(zrow + 32);
    {
        const f16x8* aps = reinterpret_cast<const f16x8*>(aph);
        a0 = a0 * aps[lg];
        a1 = a1 * aps[4 + lg];
    }

    const f16x8* wa = reinterpret_cast<const f16x8*>(wfA) + lane;
    const f16x8* wsp = reinterpret_cast<const f16x8*>(wfS) + lane;

    f32x4 accA[4], accS[4];
#pragma unroll
    for (int c = 0; c < 4; c++) {
        f32x4 t = {0.f, 0.f, 0.f, 0.f};
        t = __builtin_amdgcn_mfma_f32_16x16x32_f16(a0, wa[(0 * 4 + c) * 64], t, 0, 0, 0);
        t = __builtin_amdgcn_mfma_f32_16x16x32_f16(a1, wa[(1 * 4 + c) * 64], t, 0, 0, 0);
        accA[c] = t;
        f32x4 t2 = {0.f, 0.f, 0.f, 0.f};
        t2 = __builtin_amdgcn_mfma_f32_16x16x32_f16(a0, wsp[(0 * 4 + c) * 64], t2, 0, 0, 0);
        t2 = __builtin_amdgcn_mfma_f32_16x16x32_f16(a1, wsp[(1 * 4 + c) * 64], t2, 0, 0, 0);
        accS[c] = t2;
    }

    int rowbase = tb + wv * 16 + lg * 4;
    float qv[4], dv[4];
    bool vld[4];
#pragma unroll
    for (int r = 0; r < 4; r++) {
        int row = rowbase + r;
        vld[r] = row < N;
        qv[r] = vld[r] ? q[row] : 0.f;
        dv[r] = vld[r] ? dinv[row] : 0.f;
    }
#pragma unroll
    for (int c = 0; c < 4; c++) {
        int col = c * 16 + l15;
        float bcA = bA[col], ucA = usA[col];
        float bcS = bS[col], ucS = usS[col];
#pragma unroll
        for (int r = 0; r < 4; r++) {
            if (!vld[r]) continue;
            int row = rowbase + r;
            float oA = fmaf(qv[r], ucA, accA[c][r] + bcA);
            float oS = fmaf(qv[r], ucS, accS[c][r] + bcS);
            float aA = sigmoidf_(oA);
            float aS = sigmoidf_(oS);
            outAB[((size_t)row << 7) + col] = f2h(aA * dv[r]);
            outAB[((size_t)row << 7) + 64 + col] = f2h(aS * dv[r]);
        }
    }
}

// out_enc = (act*dinv stored fp16) * rdinv * A + C, affine computed inline
__global__ __launch_bounds__(256) void bn_apply_h(const ushort* __restrict__ actd,
                                                  const float* __restrict__ rdinv,
                                                  const float* __restrict__ st0,
                                                  const float* __restrict__ st1,
                                                  const float* __restrict__ gamma,
                                                  const float* __restrict__ beta,
                                                  float* __restrict__ out,
                                                  float invN, int N16) {
    __shared__ float As[64], Cs[64];
    int t = threadIdx.x;
    if (t < 64) {
        float m = st0[t] * invN;
        float var = st1[t] * invN - m * m;
        float a = rsqrtf(var + 1e-4f) * gamma[t];
        As[t] = a;
        Cs[t] = fmaf(-m, a, beta[t]);
    }
    __syncthreads();
    int p = blockIdx.x * 256 + t;
    if (p >= N16) return;
    int n = p >> 4;
    int cb = (p & 15) * 4;
    float r = rdinv[n];
    ushort4 v = reinterpret_cast<const ushort4*>(actd)[p];
    float4 o;
    o.x = fmaf(h2f(v.x) * r, As[cb + 0], Cs[cb + 0]);
    o.y = fmaf(h2f(v.y) * r, As[cb + 1], Cs[cb + 1]);
    o.z = fmaf(h2f(v.z) * r, As[cb + 2], Cs[cb + 2]);
    o.w = fmaf(h2f(v.w) * r, As[cb + 3], Cs[cb + 3]);
    reinterpret_cast<float4*>(out)[p] = o;
}

// out = act(fp16) * A + C, affine computed inline
__global__ __launch_bounds__(256) void bn_apply_hf(const ushort* __restrict__ acth,
                                                   const float* __restrict__ st0,
                                                   const float* __restrict__ st1,
                                                   const float* __restrict__ gamma,
                                                   const float* __restrict__ beta,
                                                   float* __restrict__ out,
                                                   float invN, int N16) {
    __shared__ float As[64], Cs[64];
    int t = threadIdx.x;
    if (t < 64) {
        float m = st0[t] * invN;
        float var = st1[t] * invN - m * m;
        float a = rsqrtf(var + 1e-4f) * gamma[t];
        As[t] = a;
        Cs[t] = fmaf(-m, a, beta[t]);
    }
    __syncthreads();
    int p = blockIdx.x * 256 + t;
    if (p >= N16) return;
    int cb = (p & 15) * 4;
    ushort4 v = reinterpret_cast<const ushort4*>(acth)[p];
    float4 o;
    o.x = fmaf(h2f(v.x), As[cb + 0], Cs[cb + 0]);
    o.y = fmaf(h2f(v.y), As[cb + 1], Cs[cb + 1]);
    o.z = fmaf(h2f(v.z), As[cb + 2], Cs[cb + 2]);
    o.w = fmaf(h2f(v.w), As[cb + 3], Cs[cb + 3]);
    reinterpret_cast<float4*>(out)[p] = o;
}

// ---------------- launch ----------------

extern "C" void kernel_launch(void* const* d_in, const int* in_sizes, int n_in,
                              void* d_out, int out_size, void* d_ws, size_t ws_size,
                              hipStream_t stream) {
    const int N = in_sizes[0] / D;
    const int E = in_sizes[1] / 2;

    const float* x = (const float*)d_in[0];
    const int* ei = (const int*)d_in[1];
    const int* src_in = ei;
    const int* dst_in = ei + E;
    const float* encW = (const float*)d_in[3];
    const float* encb = (const float*)d_in[4];
    const float* encg = (const float*)d_in[5];
    const float* encbe = (const float*)d_in[6];
    const float* attW = (const float*)d_in[7];
    const float* attb = (const float*)d_in[8];
    const float* attg = (const float*)d_in[9];
    const float* attbe = (const float*)d_in[10];
    const float* strW = (const float*)d_in[11];
    const float* strb = (const float*)d_in[12];
    const float* strg = (const float*)d_in[13];
    const float* strbe = (const float*)d_in[14];

    const int NB = (N + 1023) >> 10;
    int CAP = (E + NB - 1) / NB;
    CAP = CAP + CAP / 8 + 256;
    CAP = (CAP + 255) & ~255;

    char* ws = (char*)d_ws;
    size_t off = 0;
    auto alloc = [&](size_t bytes) -> char* {
        char* p = ws + off;
        off += (bytes + 255) & ~(size_t)255;
        return p;
    };
    int* csr = (int*)alloc((size_t)(N + 1) * 4);
    int* bcur = (int*)alloc(128 * 4);
    int* boff = (int*)alloc(128 * 4);
    float* dinv = (float*)alloc((size_t)N * 4);
    float* rdinv = (float*)alloc((size_t)N * 4);
    float* q = (float*)alloc((size_t)N * 4);
    float* stats = (float*)alloc(6 * 128 * 4);
    ushort* wf = (ushort*)alloc(6 * 4096 * 2);
    int* sorted = (int*)alloc((size_t)E * 4);
    ushort* zh = (ushort*)alloc((size_t)(N + 64) * 64 * 2);
    size_t binbytes = (size_t)NB * CAP * 4;
    size_t zabbytes = (size_t)(N + 64) * 128 * 2;
    char* region = alloc(binbytes > zabbytes ? binbytes : zabbytes);
    uint* bins = (uint*)region;
    ushort* zab = (ushort*)region;
    ushort* hA = (ushort*)alloc((size_t)(N + 64) * 64 * 2);
    ushort* hB = (ushort*)alloc((size_t)(N + 64) * 64 * 2);
    ushort* hAB = (ushort*)alloc((size_t)(N + 64) * 128 * 2);

    float* out_str = (float*)d_out;
    float* out_att = out_str + (size_t)N * D;
    float* out_enc = out_att + (size_t)N * D;

    hipMemsetAsync(bcur, 0, 128 * 4, stream);
    hipMemsetAsync(stats, 0, 6 * 128 * 4, stream);

    int N16 = N * 16;
    int g16 = (N16 + 255) / 256;
    int gT = (N + 63) / 64;
    float invN = 1.0f / (float)N;

    ushort* wf0 = wf + 0 * 4096;
    ushort* wf1 = wf + 1 * 4096;
    ushort* wf2 = wf + 2 * 4096;
    ushort* wf3 = wf + 3 * 4096;
    ushort* wf4 = wf + 4 * 4096;
    ushort* wf5 = wf + 5 * 4096;

    // ---- CSR build ----
    bin_edges<<<(E + BCH - 1) / BCH, 256, 0, stream>>>(src_in, dst_in, bcur,
                                                       bins, CAP, E);
    scan_nb<<<1, 128, 0, stream>>>(bcur, boff, csr, NB, N, E);
    build_csr<<<NB, 256, 0, stream>>>(bins, bcur, boff, csr, sorted,
                                      dinv, rdinv, CAP, N);

    // ---- prep ----
    prep_xd<<<g16, 256, 0, stream>>>(x, dinv, hA, N16);
    wprep6<<<96, 256, 0, stream>>>(encW, attW, strW, wf);

    // ---- encoder layer 1 (q fused into first gather) ----
    agg_g<<<2048, 256, 0, stream>>>(hA, csr, sorted, dinv, rdinv, zh,
                                    nullptr, nullptr, q, N, E);
    gemm_mfma<0, false, 0><<<gT, 256, 0, stream>>>(zh, 64, wf0,
                                                   nullptr, nullptr, nullptr, nullptr,
                                                   nullptr, encb, q, dinv, hB, 64,
                                                   nullptr, nullptr, invN, N);
    // ---- encoder layer 2 ----
    agg_g<<<2048, 256, 0, stream>>>(hB, csr, sorted, dinv, rdinv, zh,
                                    stats + 0, stats + 64, nullptr, N, E);
    gemm_mfma<0, true, 0><<<gT, 256, 0, stream>>>(zh, 64, wf1,
                                                  stats + 0, stats + 64, encg, encbe,
                                                  encW + 4096, encb + 64, q, dinv,
                                                  hA, 64, nullptr, nullptr, invN, N);
    // ---- z2 = Agg(x_enc act); enc2 stats ----
    agg_g<<<2048, 256, 0, stream>>>(hA, csr, sorted, dinv, rdinv, zh,
                                    stats + 128, stats + 192, nullptr, N, E);
    bn_apply_h<<<g16, 256, 0, stream>>>(hA, rdinv, stats + 128, stats + 192,
                                        encg + 64, encbe + 64, out_enc, invN, N16);
    gemm_dual<<<gT, 256, 0, stream>>>(zh, wf2, wf3, stats + 128, stats + 192,
                                      encg + 64, encbe + 64, attW, strW,
                                      attb, strb, q, dinv, hAB, invN, N);
    // ---- fused att1|str1 gather (+ both stats) ----
    agg_dual<<<2048, 256, 0, stream>>>(hAB, csr, sorted, dinv, rdinv, zab,
                                       stats + 256, stats + 320,
                                       stats + 512, stats + 576, N, E);
    // ---- attribute layer 2 ----
    gemm_mfma<1, true, 1><<<gT, 256, 0, stream>>>(zab, 128, wf4,
                                                  stats + 256, stats + 320, attg, attbe,
                                                  attW + 4096, attb + 64, q, dinv,
                                                  hAB, 64, stats + 384, stats + 448,
                                                  invN, N);
    bn_apply_hf<<<g16, 256, 0, stream>>>(hAB, stats + 384, stats + 448,
                                         attg + 64, attbe + 64, out_att, invN, N16);
    // ---- structure layer 2 ----
    gemm_mfma<2, true, 1><<<gT, 256, 0, stream>>>(zab + 64, 128, wf5,
                                                  stats + 512, stats + 576, strg, strbe,
                                                  strW + 4096, strb + 64, q, dinv,
                                                  hA, 64, stats + 640, stats + 704,
                                                  invN, N);
    bn_apply_hf<<<g16, 256, 0, stream>>>(hA, stats + 640, stats + 704,
                                         strg + 64, strbe + 64, out_str, invN, N16);
}